// Round 1
// baseline (1221.273 us; speedup 1.0000x reference)
//
#include <hip/hip_runtime.h>

// GAT 3-layer forward on MI355X.
// Strategy: CSR-by-dst (built per call) + wave-per-node softmax/aggregation (no float
// atomics), bf16 MFMA GEMMs with split-hi/lo weights for accuracy, PairNorm epilogues
// writing next-layer input directly as bf16.

typedef __attribute__((ext_vector_type(8))) short s8v;
typedef __attribute__((ext_vector_type(4))) float f4v;

__device__ __forceinline__ unsigned short f2bf(float f) {
  unsigned int x = __float_as_uint(f);
  x += 0x7fffu + ((x >> 16) & 1u);          // RTNE
  return (unsigned short)(x >> 16);
}
__device__ __forceinline__ float bf2f(unsigned short u) {
  return __uint_as_float(((unsigned int)u) << 16);
}
__device__ __forceinline__ float lrelu(float x) { return x > 0.f ? x : 0.2f * x; }
__device__ __forceinline__ float elu1(float x) { return x > 0.f ? x : expm1f(x); }

// ---------------- CSR build ----------------
__global__ __launch_bounds__(256) void hist_k(const int* __restrict__ dst, int* __restrict__ counts, int E) {
  int t = blockIdx.x * 256 + threadIdx.x;
  if (t < E) atomicAdd(&counts[dst[t]], 1);
}

__global__ __launch_bounds__(256) void scan1(const int* __restrict__ counts, int* __restrict__ row_start,
                                             int* __restrict__ bsum, int Nn) {
  __shared__ int s[256];
  int t = threadIdx.x;
  int base = blockIdx.x * 1024 + t * 4;
  int v0 = (base + 0 < Nn) ? counts[base + 0] : 0;
  int v1 = (base + 1 < Nn) ? counts[base + 1] : 0;
  int v2 = (base + 2 < Nn) ? counts[base + 2] : 0;
  int v3 = (base + 3 < Nn) ? counts[base + 3] : 0;
  s[t] = v0 + v1 + v2 + v3;
  __syncthreads();
  for (int off = 1; off < 256; off <<= 1) {
    int xv = (t >= off) ? s[t - off] : 0;
    __syncthreads();
    s[t] += xv;
    __syncthreads();
  }
  int excl = t ? s[t - 1] : 0;
  if (t == 255) bsum[blockIdx.x] = s[255];
  if (base + 0 < Nn) { row_start[base + 0] = excl; excl += v0; }
  if (base + 1 < Nn) { row_start[base + 1] = excl; excl += v1; }
  if (base + 2 < Nn) { row_start[base + 2] = excl; excl += v2; }
  if (base + 3 < Nn) { row_start[base + 3] = excl; }
}

__global__ __launch_bounds__(128) void scan2(int* __restrict__ bsum, int nb) {
  __shared__ int s[128];
  int t = threadIdx.x;
  s[t] = (t < nb) ? bsum[t] : 0;
  __syncthreads();
  for (int off = 1; off < 128; off <<= 1) {
    int xv = (t >= off) ? s[t - off] : 0;
    __syncthreads();
    s[t] += xv;
    __syncthreads();
  }
  if (t < nb) bsum[t] = t ? s[t - 1] : 0;
}

__global__ __launch_bounds__(256) void scan3(int* __restrict__ row_start, const int* __restrict__ bsum,
                                             int* __restrict__ cursor, int Nn) {
  int t = blockIdx.x * 256 + threadIdx.x;
  if (t < Nn) {
    int v = row_start[t] + bsum[t >> 10];
    row_start[t] = v;
    cursor[t] = v;
  }
}

__global__ __launch_bounds__(256) void scatter_k(const int* __restrict__ src, const int* __restrict__ dst,
                                                 int* __restrict__ cursor, int* __restrict__ csr_src, int E) {
  int t = blockIdx.x * 256 + threadIdx.x;
  if (t < E) {
    int d = dst[t];
    int pos = atomicAdd(&cursor[d], 1);
    csr_src[pos] = src[t];
  }
}

// ---------------- weight packing (transposed, bf16 hi+lo planes) ----------------
// out layout: plane0 (hi) [M][K], plane1 (lo) [M][K] at offset M*K.
__global__ __launch_bounds__(256) void pack_wt(const float* __restrict__ W, const float* __restrict__ Wres,
                                               unsigned short* __restrict__ out, int K, int M, int Mhalf) {
  int t = blockIdx.x * 256 + threadIdx.x;
  if (t >= K * M) return;
  int c = t / K, k = t - c * K;
  float v = (c < Mhalf) ? W[k * Mhalf + c] : Wres[k * Mhalf + (c - Mhalf)];
  unsigned short hi = f2bf(v);
  out[c * K + k] = hi;
  out[M * K + c * K + k] = f2bf(v - bf2f(hi));
}

__global__ __launch_bounds__(256) void cast_f2bf_k(const float* __restrict__ x, unsigned short* __restrict__ y, int n) {
  int t = blockIdx.x * 256 + threadIdx.x;
  if (t < n) y[t] = f2bf(x[t]);
}

// ---------------- GEMM: C[N,M] = A[N,K](bf16) @ Bt[M,K](bf16 hi+lo) ----------------
// mfma_f32_16x16x32_bf16: A frag lane holds A[m=lane&15][k=(lane>>4)*8+j];
// B frag lane holds B[k=(lane>>4)*8+j][n=lane&15]  (== Bt[n][k], contiguous 16B);
// C/D: col=lane&15, row=(lane>>4)*4+reg.   Requires N % 16 == 0 (100000 = 6250*16).
template <int K, int M>
__global__ __launch_bounds__(256) void gemm_bf16(const unsigned short* __restrict__ A,
                                                 const unsigned short* __restrict__ Bt,
                                                 float* __restrict__ C, int nRowTiles) {
  int wave = (int)((blockIdx.x * blockDim.x + threadIdx.x) >> 6);
  if (wave >= nRowTiles) return;
  int lane = threadIdx.x & 63;
  int r = lane & 15, q = lane >> 4;
  const unsigned short* arow = A + (size_t)(wave * 16 + r) * K + q * 8;
  s8v afrag[K / 32];
#pragma unroll
  for (int kk = 0; kk < K / 32; kk++) afrag[kk] = *(const s8v*)(arow + kk * 32);
#pragma unroll
  for (int ct = 0; ct < M / 16; ct++) {
    const unsigned short* brow = Bt + (size_t)(ct * 16 + r) * K + q * 8;
    f4v acc = {0.f, 0.f, 0.f, 0.f};
#pragma unroll
    for (int kk = 0; kk < K / 32; kk++) {
      s8v bhi = *(const s8v*)(brow + kk * 32);
      s8v blo = *(const s8v*)(brow + M * K + kk * 32);
      acc = __builtin_amdgcn_mfma_f32_16x16x32_bf16(afrag[kk], bhi, acc, 0, 0, 0);
      acc = __builtin_amdgcn_mfma_f32_16x16x32_bf16(afrag[kk], blo, acc, 0, 0, 0);
    }
    float* cp = C + (size_t)(wave * 16 + q * 4) * M + ct * 16 + r;
#pragma unroll
    for (int i = 0; i < 4; i++) cp[(size_t)i * M] = acc[i];
  }
}

// ---------------- el/er: dot(feat[n,h,:], al/ar[h,:]) ----------------
template <int H, int FS>
__global__ __launch_bounds__(256) void eler_k(const float* __restrict__ feat, const float* __restrict__ al,
                                              const float* __restrict__ ar, float* __restrict__ el,
                                              float* __restrict__ er, int Nn) {
  int t = blockIdx.x * 256 + threadIdx.x;
  if (t >= Nn * H) return;
  int n = t / H, h = t - n * H;
  const float* f = feat + (size_t)n * FS + h * 32;
  float sl = 0.f, sr = 0.f;
#pragma unroll
  for (int d = 0; d < 32; d++) {
    float v = f[d];
    sl += v * al[h * 32 + d];
    sr += v * ar[h * 32 + d];
  }
  el[t] = sl;
  er[t] = sr;
}

// ---------------- aggregation: wave per dst node, H=4, D=32 ----------------
template <int FS>
__global__ __launch_bounds__(256) void aggregate4(const float* __restrict__ feat, const float* __restrict__ el,
                                                  const float* __restrict__ er, const int* __restrict__ csr_src,
                                                  const int* __restrict__ row_start, const int* __restrict__ counts,
                                                  float* __restrict__ rst, int Nn) {
  int n = (int)((blockIdx.x * blockDim.x + threadIdx.x) >> 6);
  if (n >= Nn) return;
  int lane = threadIdx.x & 63;
  int deg = counts[n], start = row_start[n];
  int h = lane & 3, slot = lane >> 2;              // pass A/B layout: 16 edge slots x 4 heads
  float ern = er[n * 4 + h];
  float m = -__builtin_inff();
  for (int i = slot; i < deg; i += 16) {
    int s = csr_src[start + i];
    m = fmaxf(m, lrelu(el[s * 4 + h] + ern));
  }
  for (int off = 4; off < 64; off <<= 1) m = fmaxf(m, __shfl_xor(m, off));
  float dsum = 0.f;
  for (int i = slot; i < deg; i += 16) {
    int s = csr_src[start + i];
    dsum += __expf(lrelu(el[s * 4 + h] + ern) - m);
  }
  for (int off = 4; off < 64; off <<= 1) dsum += __shfl_xor(dsum, off);
  float inv = dsum > 0.f ? 1.f / dsum : 0.f;
  // pass C layout: lane -> (h0 = lane>>5 in {0,1}, d = lane&31), also handles h1 = h0+2
  int d = lane & 31, h0 = lane >> 5, h1 = h0 + 2;
  float m0 = __shfl(m, h0), m1 = __shfl(m, h1);    // lane L holds reduction for head L&3
  float i0 = __shfl(inv, h0), i1 = __shfl(inv, h1);
  float er0 = __shfl(ern, h0), er1 = __shfl(ern, h1);
  float acc0 = 0.f, acc1 = 0.f;
  for (int i = 0; i < deg; i++) {
    int s = csr_src[start + i];
    float a0 = __expf(lrelu(el[s * 4 + h0] + er0) - m0) * i0;
    float a1 = __expf(lrelu(el[s * 4 + h1] + er1) - m1) * i1;
    acc0 += a0 * feat[(size_t)s * FS + h0 * 32 + d];
    acc1 += a1 * feat[(size_t)s * FS + h1 * 32 + d];
  }
  rst[(size_t)n * 128 + h0 * 32 + d] = acc0;
  rst[(size_t)n * 128 + h1 * 32 + d] = acc1;
}

// ---------------- aggregation H=1, D=32 (layer 2), rst stride 32 ----------------
template <int FS>
__global__ __launch_bounds__(256) void aggregate1(const float* __restrict__ feat, const float* __restrict__ el,
                                                  const float* __restrict__ er, const int* __restrict__ csr_src,
                                                  const int* __restrict__ row_start, const int* __restrict__ counts,
                                                  float* __restrict__ rst, int Nn) {
  int n = (int)((blockIdx.x * blockDim.x + threadIdx.x) >> 6);
  if (n >= Nn) return;
  int lane = threadIdx.x & 63;
  int deg = counts[n], start = row_start[n];
  float ern = er[n];
  float m = -__builtin_inff();
  for (int i = lane; i < deg; i += 64) {
    int s = csr_src[start + i];
    m = fmaxf(m, lrelu(el[s] + ern));
  }
  for (int off = 1; off < 64; off <<= 1) m = fmaxf(m, __shfl_xor(m, off));
  float dsum = 0.f;
  for (int i = lane; i < deg; i += 64) {
    int s = csr_src[start + i];
    dsum += __expf(lrelu(el[s] + ern) - m);
  }
  for (int off = 1; off < 64; off <<= 1) dsum += __shfl_xor(dsum, off);
  float inv = dsum > 0.f ? 1.f / dsum : 0.f;
  int d = lane & 31, half = lane >> 5;
  float acc = 0.f;
  for (int i = half; i < deg; i += 2) {
    int s = csr_src[start + i];
    float a = __expf(lrelu(el[s] + ern) - m) * inv;
    acc += a * feat[(size_t)s * FS + d];
  }
  acc += __shfl_xor(acc, 32);
  if (lane < 32) rst[(size_t)n * 32 + d] = acc;
}

// ---------------- epilogue pass 1: col sums + row norms ----------------
// MODE 0: v = elu(rst)          (layer 0)
// MODE 1: v = elu(elu(rst+res)) (layer 1; res = feat[:,128:256], stride 256)
template <int MODE>
__global__ __launch_bounds__(256) void ep_pass1(const float* __restrict__ rst, const float* __restrict__ feat,
                                                float* __restrict__ colsum, float* __restrict__ rn_inv, int Nn) {
  __shared__ float ls[128];
  int tid = threadIdx.x;
  if (tid < 128) ls[tid] = 0.f;
  __syncthreads();
  int lane = tid & 63, w = tid >> 6;
  float cs0 = 0.f, cs1 = 0.f;
  for (int rr = 0; rr < 16; rr++) {
    int n = blockIdx.x * 64 + w * 16 + rr;
    if (n >= Nn) break;
    float v0, v1;
    if (MODE == 0) {
      v0 = elu1(rst[(size_t)n * 128 + lane]);
      v1 = elu1(rst[(size_t)n * 128 + lane + 64]);
    } else {
      v0 = elu1(elu1(rst[(size_t)n * 128 + lane] + feat[(size_t)n * 256 + 128 + lane]));
      v1 = elu1(elu1(rst[(size_t)n * 128 + lane + 64] + feat[(size_t)n * 256 + 192 + lane]));
    }
    float ss = v0 * v0 + v1 * v1;
    for (int off = 1; off < 64; off <<= 1) ss += __shfl_xor(ss, off);
    if (lane == 0) rn_inv[n] = 1.f / sqrtf(1e-6f + ss);
    cs0 += v0;
    cs1 += v1;
  }
  atomicAdd(&ls[lane], cs0);
  atomicAdd(&ls[lane + 64], cs1);
  __syncthreads();
  if (tid < 128) atomicAdd(&colsum[tid], ls[tid]);
}

// ---------------- epilogue pass 2: normalize, write bf16 next-layer input ----------------
template <int MODE>
__global__ __launch_bounds__(256) void ep_pass2(const float* __restrict__ rst, const float* __restrict__ feat,
                                                const float* __restrict__ colsum, const float* __restrict__ rn_inv,
                                                unsigned short* __restrict__ hbf, int Nn, float invN) {
  int t = blockIdx.x * 256 + threadIdx.x;
  if (t >= Nn * 128) return;
  int n = t >> 7, c = t & 127;
  float v;
  if (MODE == 0) v = elu1(rst[t]);
  else v = elu1(elu1(rst[t] + feat[(size_t)n * 256 + 128 + c]));
  float outv = v * rn_inv[n] - colsum[c] * invN;
  hbf[t] = f2bf(outv);
}

// ---------------- final: mean over nodes of (rst2 + res2) ----------------
__global__ __launch_bounds__(256) void final_reduce(const float* __restrict__ rst2, const float* __restrict__ feat2,
                                                    float* __restrict__ outsum, int Nn) {
  __shared__ float ls[32];
  if (threadIdx.x < 32) ls[threadIdx.x] = 0.f;
  __syncthreads();
  int d = threadIdx.x & 31, rl = threadIdx.x >> 5;
  float acc = 0.f;
  for (int n = blockIdx.x * 8 + rl; n < Nn; n += gridDim.x * 8)
    acc += rst2[(size_t)n * 32 + d] + feat2[(size_t)n * 64 + 32 + d];
  atomicAdd(&ls[d], acc);
  __syncthreads();
  if (threadIdx.x < 32) atomicAdd(&outsum[threadIdx.x], ls[threadIdx.x]);
}

__global__ void finalize_k(const float* __restrict__ outsum, float* __restrict__ out, float invN) {
  int t = threadIdx.x;
  if (t < 32) out[t] = outsum[t] * invN;
}

// ---------------- launcher ----------------
extern "C" void kernel_launch(void* const* d_in, const int* in_sizes, int n_in,
                              void* d_out, int out_size, void* d_ws, size_t ws_size,
                              hipStream_t stream) {
  const float* x     = (const float*)d_in[0];
  const int*   src   = (const int*)d_in[1];
  const int*   dst   = (const int*)d_in[2];
  const float* W0    = (const float*)d_in[3];
  const float* al0   = (const float*)d_in[4];
  const float* ar0   = (const float*)d_in[5];
  const float* W1    = (const float*)d_in[6];
  const float* al1   = (const float*)d_in[7];
  const float* ar1   = (const float*)d_in[8];
  const float* resW1 = (const float*)d_in[9];
  const float* W2    = (const float*)d_in[10];
  const float* al2   = (const float*)d_in[11];
  const float* ar2   = (const float*)d_in[12];
  const float* resW2 = (const float*)d_in[13];
  const int N = in_sizes[0] / 64;   // 100000
  const int E = in_sizes[1];        // 1600000
  const float invN = 1.f / (float)N;

  char* p = (char*)d_ws;
  auto alloc = [&](size_t bytes) { char* r = p; p += (bytes + 255) & ~(size_t)255; return r; };

  // zero-initialized region (one memset)
  char* zbase = p;
  int*   counts  = (int*)alloc((size_t)4 * N);
  float* colsumA = (float*)alloc(512);
  float* colsumB = (float*)alloc(512);
  float* outsum  = (float*)alloc(128);
  size_t zbytes = (size_t)(p - zbase);

  int* row_start = (int*)alloc((size_t)4 * N);
  int* cursor    = (int*)alloc((size_t)4 * N);
  int* bsum      = (int*)alloc(512);
  int* csr_src   = (int*)alloc((size_t)4 * E);
  unsigned short* hbf = (unsigned short*)alloc((size_t)2 * N * 128);
  unsigned short* w0t = (unsigned short*)alloc((size_t)2 * 2 * 128 * 64);
  unsigned short* w1t = (unsigned short*)alloc((size_t)2 * 2 * 256 * 128);
  unsigned short* w2t = (unsigned short*)alloc((size_t)2 * 2 * 64 * 128);
  float* feat   = (float*)alloc((size_t)4 * N * 256);
  float* rst    = (float*)alloc((size_t)4 * N * 128);
  float* el     = (float*)alloc((size_t)4 * N * 4);
  float* er     = (float*)alloc((size_t)4 * N * 4);
  float* rn_inv = (float*)alloc((size_t)4 * N);

  hipMemsetAsync(zbase, 0, zbytes, stream);

  // CSR build
  int eb = (E + 255) / 256;
  int nb1024 = (N + 1023) / 1024;
  hist_k<<<eb, 256, 0, stream>>>(dst, counts, E);
  scan1<<<nb1024, 256, 0, stream>>>(counts, row_start, bsum, N);
  scan2<<<1, 128, 0, stream>>>(bsum, nb1024);
  scan3<<<(N + 255) / 256, 256, 0, stream>>>(row_start, bsum, cursor, N);
  scatter_k<<<eb, 256, 0, stream>>>(src, dst, cursor, csr_src, E);

  // weights (transposed, fused [W|res], bf16 hi+lo) + input cast
  pack_wt<<<(128 * 64 + 255) / 256, 256, 0, stream>>>(W0, W0, w0t, 64, 128, 128);
  pack_wt<<<(256 * 128 + 255) / 256, 256, 0, stream>>>(W1, resW1, w1t, 128, 256, 128);
  pack_wt<<<(64 * 128 + 255) / 256, 256, 0, stream>>>(W2, resW2, w2t, 128, 64, 32);
  cast_f2bf_k<<<(N * 64 + 255) / 256, 256, 0, stream>>>(x, hbf, N * 64);

  const int rowTiles = N / 16;            // N % 16 == 0 (100000)
  const int gblocks = (rowTiles + 3) / 4; // 4 waves/block, wave = 16 rows x all M cols
  const int aggblocks = (N + 3) / 4;      // wave per node

  // Layer 0: GATConv(64 -> 4x32), no residual
  gemm_bf16<64, 128><<<gblocks, 256, 0, stream>>>(hbf, w0t, feat, rowTiles);
  eler_k<4, 128><<<(N * 4 + 255) / 256, 256, 0, stream>>>(feat, al0, ar0, el, er, N);
  aggregate4<128><<<aggblocks, 256, 0, stream>>>(feat, el, er, csr_src, row_start, counts, rst, N);
  ep_pass1<0><<<(N + 63) / 64, 256, 0, stream>>>(rst, nullptr, colsumA, rn_inv, N);
  ep_pass2<0><<<(N * 128 + 255) / 256, 256, 0, stream>>>(rst, nullptr, colsumA, rn_inv, hbf, N, invN);

  // Layer 1: GATConv(128 -> 4x32) + residual, elu(elu(.))
  gemm_bf16<128, 256><<<gblocks, 256, 0, stream>>>(hbf, w1t, feat, rowTiles);
  eler_k<4, 256><<<(N * 4 + 255) / 256, 256, 0, stream>>>(feat, al1, ar1, el, er, N);
  aggregate4<256><<<aggblocks, 256, 0, stream>>>(feat, el, er, csr_src, row_start, counts, rst, N);
  ep_pass1<1><<<(N + 63) / 64, 256, 0, stream>>>(rst, feat, colsumB, rn_inv, N);
  ep_pass2<1><<<(N * 128 + 255) / 256, 256, 0, stream>>>(rst, feat, colsumB, rn_inv, hbf, N, invN);

  // Layer 2: GATConv(128 -> 1x32) + residual, then mean over nodes
  gemm_bf16<128, 64><<<gblocks, 256, 0, stream>>>(hbf, w2t, feat, rowTiles);
  eler_k<1, 64><<<(N + 255) / 256, 256, 0, stream>>>(feat, al2, ar2, el, er, N);
  aggregate1<64><<<aggblocks, 256, 0, stream>>>(feat, el, er, csr_src, row_start, counts, rst, N);
  final_reduce<<<512, 256, 0, stream>>>(rst, feat, outsum, N);
  finalize_k<<<1, 64, 0, stream>>>(outsum, (float*)d_out, invN);
}

// Round 2
// 988.996 us; speedup vs baseline: 1.2349x; 1.2349x over previous
//
#include <hip/hip_runtime.h>

// GAT 3-layer forward on MI355X — round 2.
// vs round 1: no-max softmax (numerically safe, removes one gather pass), alpha computed
// once per (edge,head) and broadcast via shuffle (removes 32x-redundant exp in the hot
// loop), bf16 feature gather table written by the GEMM epilogue (halves gather bytes),
// GEMM with 5 row-tiles/wave (5x B reuse), fp32 feat kept only for residual halves.

typedef __attribute__((ext_vector_type(8))) short s8v;
typedef __attribute__((ext_vector_type(4))) float f4v;

__device__ __forceinline__ unsigned short f2bf(float f) {
  unsigned int x = __float_as_uint(f);
  x += 0x7fffu + ((x >> 16) & 1u);          // RTNE
  return (unsigned short)(x >> 16);
}
__device__ __forceinline__ float bf2f(unsigned short u) {
  return __uint_as_float(((unsigned int)u) << 16);
}
__device__ __forceinline__ float lrelu(float x) { return x > 0.f ? x : 0.2f * x; }
__device__ __forceinline__ float elu1(float x) { return x > 0.f ? x : expm1f(x); }

// ---------------- CSR build ----------------
__global__ __launch_bounds__(256) void hist_k(const int* __restrict__ dst, int* __restrict__ counts, int E) {
  int t = blockIdx.x * 256 + threadIdx.x;
  if (t < E) atomicAdd(&counts[dst[t]], 1);
}

__global__ __launch_bounds__(256) void scan1(const int* __restrict__ counts, int* __restrict__ row_start,
                                             int* __restrict__ bsum, int Nn) {
  __shared__ int s[256];
  int t = threadIdx.x;
  int base = blockIdx.x * 1024 + t * 4;
  int v0 = (base + 0 < Nn) ? counts[base + 0] : 0;
  int v1 = (base + 1 < Nn) ? counts[base + 1] : 0;
  int v2 = (base + 2 < Nn) ? counts[base + 2] : 0;
  int v3 = (base + 3 < Nn) ? counts[base + 3] : 0;
  s[t] = v0 + v1 + v2 + v3;
  __syncthreads();
  for (int off = 1; off < 256; off <<= 1) {
    int xv = (t >= off) ? s[t - off] : 0;
    __syncthreads();
    s[t] += xv;
    __syncthreads();
  }
  int excl = t ? s[t - 1] : 0;
  if (t == 255) bsum[blockIdx.x] = s[255];
  if (base + 0 < Nn) { row_start[base + 0] = excl; excl += v0; }
  if (base + 1 < Nn) { row_start[base + 1] = excl; excl += v1; }
  if (base + 2 < Nn) { row_start[base + 2] = excl; excl += v2; }
  if (base + 3 < Nn) { row_start[base + 3] = excl; }
}

__global__ __launch_bounds__(128) void scan2(int* __restrict__ bsum, int nb) {
  __shared__ int s[128];
  int t = threadIdx.x;
  s[t] = (t < nb) ? bsum[t] : 0;
  __syncthreads();
  for (int off = 1; off < 128; off <<= 1) {
    int xv = (t >= off) ? s[t - off] : 0;
    __syncthreads();
    s[t] += xv;
    __syncthreads();
  }
  if (t < nb) bsum[t] = t ? s[t - 1] : 0;
}

__global__ __launch_bounds__(256) void scan3(int* __restrict__ row_start, const int* __restrict__ bsum,
                                             int* __restrict__ cursor, int Nn) {
  int t = blockIdx.x * 256 + threadIdx.x;
  if (t < Nn) {
    int v = row_start[t] + bsum[t >> 10];
    row_start[t] = v;
    cursor[t] = v;
  }
}

__global__ __launch_bounds__(256) void scatter_k(const int* __restrict__ src, const int* __restrict__ dst,
                                                 int* __restrict__ cursor, int* __restrict__ csr_src, int E) {
  int t = blockIdx.x * 256 + threadIdx.x;
  if (t < E) {
    int d = dst[t];
    int pos = atomicAdd(&cursor[d], 1);
    csr_src[pos] = src[t];
  }
}

// ---------------- weight packing (transposed, bf16 hi+lo planes) ----------------
__global__ __launch_bounds__(256) void pack_wt(const float* __restrict__ W, const float* __restrict__ Wres,
                                               unsigned short* __restrict__ out, int K, int M, int Mhalf) {
  int t = blockIdx.x * 256 + threadIdx.x;
  if (t >= K * M) return;
  int c = t / K, k = t - c * K;
  float v = (c < Mhalf) ? W[k * Mhalf + c] : Wres[k * Mhalf + (c - Mhalf)];
  unsigned short hi = f2bf(v);
  out[c * K + k] = hi;
  out[M * K + c * K + k] = f2bf(v - bf2f(hi));
}

__global__ __launch_bounds__(256) void cast_f2bf_k(const float* __restrict__ x, unsigned short* __restrict__ y, int n) {
  int t = blockIdx.x * 256 + threadIdx.x;
  if (t < n) y[t] = f2bf(x[t]);
}

// ---------------- GEMM: [N,M] = A[N,K](bf16) @ Bt[M,K](bf16 hi+lo) ----------------
// Wave handles R=5 consecutive 16-row tiles (B frags reused 5x). Outputs:
//  cols <  BF     -> featbf (bf16 gather/eler table, stride BF)
//  cols >= F32MIN -> res    (fp32 residual half, stride M-F32MIN)
template <int K, int M, int R, int BF, int F32MIN>
__global__ __launch_bounds__(256) void gemm_bf16(const unsigned short* __restrict__ A,
                                                 const unsigned short* __restrict__ Bt,
                                                 unsigned short* __restrict__ featbf,
                                                 float* __restrict__ res, int nRowTiles) {
  int wv = (int)((blockIdx.x * blockDim.x + threadIdx.x) >> 6);
  int tile0 = wv * R;
  if (tile0 >= nRowTiles) return;          // full waves only: nRowTiles % R == 0
  int lane = threadIdx.x & 63;
  int r = lane & 15, q = lane >> 4;
  s8v afrag[R][K / 32];
#pragma unroll
  for (int rr = 0; rr < R; rr++) {
    const unsigned short* arow = A + (size_t)((tile0 + rr) * 16 + r) * K + q * 8;
#pragma unroll
    for (int kk = 0; kk < K / 32; kk++) afrag[rr][kk] = *(const s8v*)(arow + kk * 32);
  }
#pragma unroll
  for (int ct = 0; ct < M / 16; ct++) {
    const unsigned short* brow = Bt + (size_t)(ct * 16 + r) * K + q * 8;
    s8v bhi[K / 32], blo[K / 32];
#pragma unroll
    for (int kk = 0; kk < K / 32; kk++) {
      bhi[kk] = *(const s8v*)(brow + kk * 32);
      blo[kk] = *(const s8v*)(brow + (size_t)M * K + kk * 32);
    }
    int col = ct * 16 + r;
#pragma unroll
    for (int rr = 0; rr < R; rr++) {
      f4v acc = {0.f, 0.f, 0.f, 0.f};
#pragma unroll
      for (int kk = 0; kk < K / 32; kk++) {
        acc = __builtin_amdgcn_mfma_f32_16x16x32_bf16(afrag[rr][kk], bhi[kk], acc, 0, 0, 0);
        acc = __builtin_amdgcn_mfma_f32_16x16x32_bf16(afrag[rr][kk], blo[kk], acc, 0, 0, 0);
      }
      int row0 = (tile0 + rr) * 16 + q * 4;
#pragma unroll
      for (int i = 0; i < 4; i++) {
        float v = acc[i];
        size_t row = (size_t)(row0 + i);
        if constexpr (BF > 0) {
          if (col < BF) featbf[row * BF + col] = f2bf(v);
        }
        if constexpr (F32MIN < M) {
          if (col >= F32MIN) res[row * (M - F32MIN) + (col - F32MIN)] = v;
        }
      }
    }
  }
}

// ---------------- el/er from bf16 feat table ----------------
template <int H, int BF>
__global__ __launch_bounds__(256) void eler_k(const unsigned short* __restrict__ featbf,
                                              const float* __restrict__ al, const float* __restrict__ ar,
                                              float* __restrict__ el, float* __restrict__ er, int Nn) {
  int t = blockIdx.x * 256 + threadIdx.x;
  if (t >= Nn * H) return;
  int n = t / H, h = t - n * H;
  const unsigned short* f = featbf + (size_t)n * BF + h * 32;
  float sl = 0.f, sr = 0.f;
#pragma unroll
  for (int v = 0; v < 4; v++) {
    s8v pk = *(const s8v*)(f + v * 8);
#pragma unroll
    for (int j = 0; j < 8; j++) {
      float x = bf2f((unsigned short)pk[j]);
      int dd = v * 8 + j;
      sl += x * al[h * 32 + dd];
      sr += x * ar[h * 32 + dd];
    }
  }
  el[t] = sl;
  er[t] = sr;
}

// ---------------- aggregation: wave per dst node, H=4, D=32 ----------------
// No-max softmax. Phase 1: denom (16 edge-slots x 4 heads). Phase 2: 16-edge chunks,
// alpha computed once per (edge,head), broadcast by shuffle; chunk 0 reuses phase-1 regs.
__global__ __launch_bounds__(256) void aggregate4(const unsigned short* __restrict__ featbf,
                                                  const float* __restrict__ el, const float* __restrict__ er,
                                                  const int* __restrict__ csr_src, const int* __restrict__ row_start,
                                                  const int* __restrict__ counts, float* __restrict__ rst, int Nn) {
  int n = (int)((blockIdx.x * blockDim.x + threadIdx.x) >> 6);
  if (n >= Nn) return;
  int lane = threadIdx.x & 63;
  int deg = counts[n], start = row_start[n];
  int h = lane & 3, slot = lane >> 2;
  float ern = er[n * 4 + h];
  // phase 1: denom, caching chunk 0
  bool v0 = slot < deg;
  int s0 = v0 ? csr_src[start + slot] : 0;
  float e0 = v0 ? __expf(lrelu(el[s0 * 4 + h] + ern)) : 0.f;
  float dsum = e0;
  for (int base = 16; base < deg; base += 16) {
    int i = base + slot;
    bool v = i < deg;
    int s = v ? csr_src[start + i] : 0;
    dsum += v ? __expf(lrelu(el[s * 4 + h] + ern)) : 0.f;
  }
#pragma unroll
  for (int off = 4; off < 64; off <<= 1) dsum += __shfl_xor(dsum, off);
  float inv = dsum > 0.f ? 1.f / dsum : 0.f;
  // phase 2
  int d = lane & 31, h0 = lane >> 5, h1 = h0 + 2;
  float acc0 = 0.f, acc1 = 0.f;
  auto inner = [&](int s_c, float ax_c, int cnt) {
    if (cnt == 16) {
#pragma unroll
      for (int j = 0; j < 16; j++) {
        int sj = __shfl(s_c, j * 4);
        float a0 = __shfl(ax_c, j * 4 + h0);
        float a1 = __shfl(ax_c, j * 4 + h1);
        const unsigned short* fp = featbf + (size_t)sj * 128 + d;
        acc0 += a0 * bf2f(fp[h0 * 32]);
        acc1 += a1 * bf2f(fp[h1 * 32]);
      }
    } else {
      for (int j = 0; j < cnt; j++) {
        int sj = __shfl(s_c, j * 4);
        float a0 = __shfl(ax_c, j * 4 + h0);
        float a1 = __shfl(ax_c, j * 4 + h1);
        const unsigned short* fp = featbf + (size_t)sj * 128 + d;
        acc0 += a0 * bf2f(fp[h0 * 32]);
        acc1 += a1 * bf2f(fp[h1 * 32]);
      }
    }
  };
  inner(s0, e0 * inv, deg < 16 ? deg : 16);
  for (int base = 16; base < deg; base += 16) {
    int i = base + slot;
    bool v = i < deg;
    int s = v ? csr_src[start + i] : 0;
    float ax = v ? __expf(lrelu(el[s * 4 + h] + ern)) * inv : 0.f;
    int rem = deg - base;
    inner(s, ax, rem < 16 ? rem : 16);
  }
  rst[(size_t)n * 128 + h0 * 32 + d] = acc0;
  rst[(size_t)n * 128 + h1 * 32 + d] = acc1;
}

// ---------------- aggregation H=1, D=32 (layer 2), featbf stride 32 ----------------
__global__ __launch_bounds__(256) void aggregate1(const unsigned short* __restrict__ featbf,
                                                  const float* __restrict__ el, const float* __restrict__ er,
                                                  const int* __restrict__ csr_src, const int* __restrict__ row_start,
                                                  const int* __restrict__ counts, float* __restrict__ rst, int Nn) {
  int n = (int)((blockIdx.x * blockDim.x + threadIdx.x) >> 6);
  if (n >= Nn) return;
  int lane = threadIdx.x & 63;
  int deg = counts[n], start = row_start[n];
  float ern = er[n];
  bool v0 = lane < deg;
  int s0 = v0 ? csr_src[start + lane] : 0;
  float e0 = v0 ? __expf(lrelu(el[s0] + ern)) : 0.f;
  float dsum = e0;
  for (int base = 64; base < deg; base += 64) {
    int i = base + lane;
    bool v = i < deg;
    int s = v ? csr_src[start + i] : 0;
    dsum += v ? __expf(lrelu(el[s] + ern)) : 0.f;
  }
#pragma unroll
  for (int off = 1; off < 64; off <<= 1) dsum += __shfl_xor(dsum, off);
  float inv = dsum > 0.f ? 1.f / dsum : 0.f;
  int d = lane & 31, half = lane >> 5;
  float acc = 0.f;
  auto inner = [&](int s_c, float ax_c, int cnt) {
    for (int j = half; j < cnt; j += 2) {
      int sj = __shfl(s_c, j);
      float a = __shfl(ax_c, j);
      acc += a * bf2f(featbf[(size_t)sj * 32 + d]);
    }
  };
  inner(s0, e0 * inv, deg < 64 ? deg : 64);
  for (int base = 64; base < deg; base += 64) {
    int i = base + lane;
    bool v = i < deg;
    int s = v ? csr_src[start + i] : 0;
    float ax = v ? __expf(lrelu(el[s] + ern)) * inv : 0.f;
    int rem = deg - base;
    inner(s, ax, rem < 64 ? rem : 64);
  }
  acc += __shfl_xor(acc, 32);
  if (lane < 32) rst[(size_t)n * 32 + d] = acc;
}

// ---------------- epilogue pass 1: col sums + row norms ----------------
// MODE 0: v = elu(rst); MODE 1: v = elu(elu(rst + res)), res compact stride 128
template <int MODE>
__global__ __launch_bounds__(256) void ep_pass1(const float* __restrict__ rst, const float* __restrict__ res,
                                                float* __restrict__ colsum, float* __restrict__ rn_inv, int Nn) {
  __shared__ float ls[128];
  int tid = threadIdx.x;
  if (tid < 128) ls[tid] = 0.f;
  __syncthreads();
  int lane = tid & 63, w = tid >> 6;
  float cs0 = 0.f, cs1 = 0.f;
  for (int rr = 0; rr < 16; rr++) {
    int n = blockIdx.x * 64 + w * 16 + rr;
    if (n >= Nn) break;
    float v0, v1;
    if (MODE == 0) {
      v0 = elu1(rst[(size_t)n * 128 + lane]);
      v1 = elu1(rst[(size_t)n * 128 + lane + 64]);
    } else {
      v0 = elu1(elu1(rst[(size_t)n * 128 + lane] + res[(size_t)n * 128 + lane]));
      v1 = elu1(elu1(rst[(size_t)n * 128 + lane + 64] + res[(size_t)n * 128 + lane + 64]));
    }
    float ss = v0 * v0 + v1 * v1;
#pragma unroll
    for (int off = 1; off < 64; off <<= 1) ss += __shfl_xor(ss, off);
    if (lane == 0) rn_inv[n] = 1.f / sqrtf(1e-6f + ss);
    cs0 += v0;
    cs1 += v1;
  }
  atomicAdd(&ls[lane], cs0);
  atomicAdd(&ls[lane + 64], cs1);
  __syncthreads();
  if (tid < 128) atomicAdd(&colsum[tid], ls[tid]);
}

// ---------------- epilogue pass 2: normalize, write bf16 next-layer input ----------------
template <int MODE>
__global__ __launch_bounds__(256) void ep_pass2(const float* __restrict__ rst, const float* __restrict__ res,
                                                const float* __restrict__ colsum, const float* __restrict__ rn_inv,
                                                unsigned short* __restrict__ hbf, int Nn, float invN) {
  int t = blockIdx.x * 256 + threadIdx.x;
  if (t >= Nn * 128) return;
  int n = t >> 7, c = t & 127;
  float v;
  if (MODE == 0) v = elu1(rst[t]);
  else v = elu1(elu1(rst[t] + res[t]));
  float outv = v * rn_inv[n] - colsum[c] * invN;
  hbf[t] = f2bf(outv);
}

// ---------------- final: mean over nodes of (rst2 + res2), both stride 32 ----------------
__global__ __launch_bounds__(256) void final_reduce(const float* __restrict__ rst2, const float* __restrict__ res2,
                                                    float* __restrict__ outsum, int Nn) {
  __shared__ float ls[32];
  if (threadIdx.x < 32) ls[threadIdx.x] = 0.f;
  __syncthreads();
  int d = threadIdx.x & 31, rl = threadIdx.x >> 5;
  float acc = 0.f;
  for (int n = blockIdx.x * 8 + rl; n < Nn; n += gridDim.x * 8)
    acc += rst2[(size_t)n * 32 + d] + res2[(size_t)n * 32 + d];
  atomicAdd(&ls[d], acc);
  __syncthreads();
  if (threadIdx.x < 32) atomicAdd(&outsum[threadIdx.x], ls[threadIdx.x]);
}

__global__ void finalize_k(const float* __restrict__ outsum, float* __restrict__ out, float invN) {
  int t = threadIdx.x;
  if (t < 32) out[t] = outsum[t] * invN;
}

// ---------------- launcher ----------------
extern "C" void kernel_launch(void* const* d_in, const int* in_sizes, int n_in,
                              void* d_out, int out_size, void* d_ws, size_t ws_size,
                              hipStream_t stream) {
  const float* x     = (const float*)d_in[0];
  const int*   src   = (const int*)d_in[1];
  const int*   dst   = (const int*)d_in[2];
  const float* W0    = (const float*)d_in[3];
  const float* al0   = (const float*)d_in[4];
  const float* ar0   = (const float*)d_in[5];
  const float* W1    = (const float*)d_in[6];
  const float* al1   = (const float*)d_in[7];
  const float* ar1   = (const float*)d_in[8];
  const float* resW1 = (const float*)d_in[9];
  const float* W2    = (const float*)d_in[10];
  const float* al2   = (const float*)d_in[11];
  const float* ar2   = (const float*)d_in[12];
  const float* resW2 = (const float*)d_in[13];
  const int N = in_sizes[0] / 64;   // 100000
  const int E = in_sizes[1];        // 1600000
  const float invN = 1.f / (float)N;

  char* p = (char*)d_ws;
  auto alloc = [&](size_t bytes) { char* r = p; p += (bytes + 255) & ~(size_t)255; return r; };

  // zero-initialized region (one memset)
  char* zbase = p;
  int*   counts  = (int*)alloc((size_t)4 * N);
  float* colsumA = (float*)alloc(512);
  float* colsumB = (float*)alloc(512);
  float* outsum  = (float*)alloc(128);
  size_t zbytes = (size_t)(p - zbase);

  int* row_start = (int*)alloc((size_t)4 * N);
  int* cursor    = (int*)alloc((size_t)4 * N);
  int* bsum      = (int*)alloc(512);
  int* csr_src   = (int*)alloc((size_t)4 * E);
  unsigned short* hbf    = (unsigned short*)alloc((size_t)2 * N * 128);
  unsigned short* featbf = (unsigned short*)alloc((size_t)2 * N * 128);
  unsigned short* w0t = (unsigned short*)alloc((size_t)2 * 2 * 128 * 64);
  unsigned short* w1t = (unsigned short*)alloc((size_t)2 * 2 * 256 * 128);
  unsigned short* w2t = (unsigned short*)alloc((size_t)2 * 2 * 64 * 128);
  float* res    = (float*)alloc((size_t)4 * N * 128);
  float* rst    = (float*)alloc((size_t)4 * N * 128);
  float* el     = (float*)alloc((size_t)4 * N * 4);
  float* er     = (float*)alloc((size_t)4 * N * 4);
  float* rn_inv = (float*)alloc((size_t)4 * N);

  hipMemsetAsync(zbase, 0, zbytes, stream);

  // CSR build
  int eb = (E + 255) / 256;
  int nb1024 = (N + 1023) / 1024;
  hist_k<<<eb, 256, 0, stream>>>(dst, counts, E);
  scan1<<<nb1024, 256, 0, stream>>>(counts, row_start, bsum, N);
  scan2<<<1, 128, 0, stream>>>(bsum, nb1024);
  scan3<<<(N + 255) / 256, 256, 0, stream>>>(row_start, bsum, cursor, N);
  scatter_k<<<eb, 256, 0, stream>>>(src, dst, cursor, csr_src, E);

  // weights (transposed, fused [W|res], bf16 hi+lo) + input cast
  pack_wt<<<(128 * 64 + 255) / 256, 256, 0, stream>>>(W0, W0, w0t, 64, 128, 128);
  pack_wt<<<(256 * 128 + 255) / 256, 256, 0, stream>>>(W1, resW1, w1t, 128, 256, 128);
  pack_wt<<<(64 * 128 + 255) / 256, 256, 0, stream>>>(W2, resW2, w2t, 128, 64, 32);
  cast_f2bf_k<<<(N * 64 + 255) / 256, 256, 0, stream>>>(x, hbf, N * 64);

  const int rowTiles = N / 16;                 // 6250, divisible by R=5
  const int R = 5;
  const int gblocks = (rowTiles / R + 3) / 4;  // 1250 waves, 4/block
  const int aggblocks = (N + 3) / 4;           // wave per node

  // Layer 0: GATConv(64 -> 4x32), no residual
  gemm_bf16<64, 128, R, 128, 128><<<gblocks, 256, 0, stream>>>(hbf, w0t, featbf, nullptr, rowTiles);
  eler_k<4, 128><<<(N * 4 + 255) / 256, 256, 0, stream>>>(featbf, al0, ar0, el, er, N);
  aggregate4<<<aggblocks, 256, 0, stream>>>(featbf, el, er, csr_src, row_start, counts, rst, N);
  ep_pass1<0><<<(N + 63) / 64, 256, 0, stream>>>(rst, nullptr, colsumA, rn_inv, N);
  ep_pass2<0><<<(N * 128 + 255) / 256, 256, 0, stream>>>(rst, nullptr, colsumA, rn_inv, hbf, N, invN);

  // Layer 1: GATConv(128 -> 4x32) + residual, elu(elu(.))
  gemm_bf16<128, 256, R, 128, 128><<<gblocks, 256, 0, stream>>>(hbf, w1t, featbf, res, rowTiles);
  eler_k<4, 128><<<(N * 4 + 255) / 256, 256, 0, stream>>>(featbf, al1, ar1, el, er, N);
  aggregate4<<<aggblocks, 256, 0, stream>>>(featbf, el, er, csr_src, row_start, counts, rst, N);
  ep_pass1<1><<<(N + 63) / 64, 256, 0, stream>>>(rst, res, colsumB, rn_inv, N);
  ep_pass2<1><<<(N * 128 + 255) / 256, 256, 0, stream>>>(rst, res, colsumB, rn_inv, hbf, N, invN);

  // Layer 2: GATConv(128 -> 1x32) + residual, then mean over nodes
  gemm_bf16<128, 64, R, 32, 32><<<gblocks, 256, 0, stream>>>(hbf, w2t, featbf, res, rowTiles);
  eler_k<1, 32><<<(N + 255) / 256, 256, 0, stream>>>(featbf, al2, ar2, el, er, N);
  aggregate1<<<aggblocks, 256, 0, stream>>>(featbf, el, er, csr_src, row_start, counts, rst, N);
  final_reduce<<<512, 256, 0, stream>>>(rst, res, outsum, N);
  finalize_k<<<1, 64, 0, stream>>>(outsum, (float*)d_out, invN);
}

// Round 3
// 796.794 us; speedup vs baseline: 1.5327x; 1.2412x over previous
//
#include <hip/hip_runtime.h>

// GAT 3-layer forward on MI355X — round 3.
// vs round 2: edge-parallel alpha pass (exp/el/er off the node critical path), dim-split
// 8B/lane feature gathers (4x fewer VMEM instrs, more MLP), el/er fused into GEMM as
// extra columns, residual+ELU+rownorm fused into aggregation epilogue, PairNorm done
// with two slim bf16 passes.

typedef __attribute__((ext_vector_type(8))) short s8v;
typedef __attribute__((ext_vector_type(4))) float f4v;

__device__ __forceinline__ unsigned short f2bf(float f) {
  unsigned int x = __float_as_uint(f);
  x += 0x7fffu + ((x >> 16) & 1u);          // RTNE
  return (unsigned short)(x >> 16);
}
__device__ __forceinline__ float bf2f(unsigned short u) {
  return __uint_as_float(((unsigned int)u) << 16);
}
__device__ __forceinline__ float lrelu(float x) { return x > 0.f ? x : 0.2f * x; }
__device__ __forceinline__ float elu1(float x) { return x > 0.f ? x : expm1f(x); }

// ---------------- CSR build ----------------
__global__ __launch_bounds__(256) void hist_k(const int* __restrict__ dst, int* __restrict__ counts, int E) {
  int t = blockIdx.x * 256 + threadIdx.x;
  if (t < E) atomicAdd(&counts[dst[t]], 1);
}

__global__ __launch_bounds__(256) void scan1(const int* __restrict__ counts, int* __restrict__ row_start,
                                             int* __restrict__ bsum, int Nn) {
  __shared__ int s[256];
  int t = threadIdx.x;
  int base = blockIdx.x * 1024 + t * 4;
  int v0 = (base + 0 < Nn) ? counts[base + 0] : 0;
  int v1 = (base + 1 < Nn) ? counts[base + 1] : 0;
  int v2 = (base + 2 < Nn) ? counts[base + 2] : 0;
  int v3 = (base + 3 < Nn) ? counts[base + 3] : 0;
  s[t] = v0 + v1 + v2 + v3;
  __syncthreads();
  for (int off = 1; off < 256; off <<= 1) {
    int xv = (t >= off) ? s[t - off] : 0;
    __syncthreads();
    s[t] += xv;
    __syncthreads();
  }
  int excl = t ? s[t - 1] : 0;
  if (t == 255) bsum[blockIdx.x] = s[255];
  if (base + 0 < Nn) { row_start[base + 0] = excl; excl += v0; }
  if (base + 1 < Nn) { row_start[base + 1] = excl; excl += v1; }
  if (base + 2 < Nn) { row_start[base + 2] = excl; excl += v2; }
  if (base + 3 < Nn) { row_start[base + 3] = excl; }
}

__global__ __launch_bounds__(128) void scan2(int* __restrict__ bsum, int nb) {
  __shared__ int s[128];
  int t = threadIdx.x;
  s[t] = (t < nb) ? bsum[t] : 0;
  __syncthreads();
  for (int off = 1; off < 128; off <<= 1) {
    int xv = (t >= off) ? s[t - off] : 0;
    __syncthreads();
    s[t] += xv;
    __syncthreads();
  }
  if (t < nb) bsum[t] = t ? s[t - 1] : 0;
}

__global__ __launch_bounds__(256) void scan3(int* __restrict__ row_start, const int* __restrict__ bsum,
                                             int* __restrict__ cursor, int Nn) {
  int t = blockIdx.x * 256 + threadIdx.x;
  if (t < Nn) {
    int v = row_start[t] + bsum[t >> 10];
    row_start[t] = v;
    cursor[t] = v;
  }
}

__global__ __launch_bounds__(256) void scatter_k(const int* __restrict__ src, const int* __restrict__ dst,
                                                 int* __restrict__ cursor, int* __restrict__ csr_src,
                                                 int* __restrict__ csr_dst, int E) {
  int t = blockIdx.x * 256 + threadIdx.x;
  if (t < E) {
    int d = dst[t];
    int pos = atomicAdd(&cursor[d], 1);
    csr_src[pos] = src[t];
    csr_dst[pos] = d;
  }
}

// ---------------- fused weight pack: [W | W@al | W@ar | pad | resW], bf16 hi+lo ----------------
__global__ __launch_bounds__(256) void fill_pack(const float* __restrict__ W, const float* __restrict__ al,
                                                 const float* __restrict__ ar, const float* __restrict__ resW,
                                                 unsigned short* __restrict__ out,
                                                 int K, int M, int BF, int H, int RES0) {
  int t = blockIdx.x * 256 + threadIdx.x;
  if (t >= K * M) return;
  int c = t / K, k = t - c * K;
  float v = 0.f;
  if (c < BF) {
    v = W[k * BF + c];
  } else if (c < BF + H) {
    int h = c - BF;
    float s = 0.f;
    for (int d = 0; d < 32; d++) s += W[k * BF + h * 32 + d] * al[h * 32 + d];
    v = s;
  } else if (c < BF + 2 * H) {
    int h = c - BF - H;
    float s = 0.f;
    for (int d = 0; d < 32; d++) s += W[k * BF + h * 32 + d] * ar[h * 32 + d];
    v = s;
  } else if (c >= RES0) {
    v = resW[k * (M - RES0) + (c - RES0)];
  }
  unsigned short hi = f2bf(v);
  out[c * K + k] = hi;
  out[M * K + c * K + k] = f2bf(v - bf2f(hi));
}

__global__ __launch_bounds__(256) void cast_f2bf_k(const float* __restrict__ x, unsigned short* __restrict__ y, int n) {
  int t = blockIdx.x * 256 + threadIdx.x;
  if (t < n) y[t] = f2bf(x[t]);
}

// ---------------- GEMM: A[N,K](bf16) @ Bt[M,K](bf16 hi+lo) ----------------
// Epilogue routes cols: [0,BF)->featbf(bf16), [BF,BF+H)->el, [BF+H,BF+2H)->er,
// [RES0,M)->res(fp32, stride M-RES0). Wave = R row-tiles (B reuse).
template <int K, int M, int R, int BF, int H, int RES0>
__global__ __launch_bounds__(256) void gemm_bf16(const unsigned short* __restrict__ A,
                                                 const unsigned short* __restrict__ Bt,
                                                 unsigned short* __restrict__ featbf,
                                                 float* __restrict__ el, float* __restrict__ er,
                                                 float* __restrict__ res, int nRowTiles) {
  int wv = (int)((blockIdx.x * blockDim.x + threadIdx.x) >> 6);
  int tile0 = wv * R;
  if (tile0 >= nRowTiles) return;
  int lane = threadIdx.x & 63;
  int r = lane & 15, q = lane >> 4;
  s8v afrag[R][K / 32];
#pragma unroll
  for (int rr = 0; rr < R; rr++) {
    const unsigned short* arow = A + (size_t)((tile0 + rr) * 16 + r) * K + q * 8;
#pragma unroll
    for (int kk = 0; kk < K / 32; kk++) afrag[rr][kk] = *(const s8v*)(arow + kk * 32);
  }
#pragma unroll
  for (int ct = 0; ct < M / 16; ct++) {
    const unsigned short* brow = Bt + (size_t)(ct * 16 + r) * K + q * 8;
    s8v bhi[K / 32], blo[K / 32];
#pragma unroll
    for (int kk = 0; kk < K / 32; kk++) {
      bhi[kk] = *(const s8v*)(brow + kk * 32);
      blo[kk] = *(const s8v*)(brow + (size_t)M * K + kk * 32);
    }
    int col = ct * 16 + r;
#pragma unroll
    for (int rr = 0; rr < R; rr++) {
      f4v acc = {0.f, 0.f, 0.f, 0.f};
#pragma unroll
      for (int kk = 0; kk < K / 32; kk++) {
        acc = __builtin_amdgcn_mfma_f32_16x16x32_bf16(afrag[rr][kk], bhi[kk], acc, 0, 0, 0);
        acc = __builtin_amdgcn_mfma_f32_16x16x32_bf16(afrag[rr][kk], blo[kk], acc, 0, 0, 0);
      }
      int row0 = (tile0 + rr) * 16 + q * 4;
#pragma unroll
      for (int i = 0; i < 4; i++) {
        float v = acc[i];
        size_t row = (size_t)(row0 + i);
        if (col < BF) {
          featbf[row * BF + col] = f2bf(v);
        } else if (col < BF + H) {
          el[row * H + (col - BF)] = v;
        } else if (col < BF + 2 * H) {
          er[row * H + (col - BF - H)] = v;
        } else if (RES0 < M && col >= RES0) {
          res[row * (M - RES0) + (col - RES0)] = v;
        }
      }
    }
  }
}

// ---------------- edge-parallel exp(lrelu(el+er)) in CSR order ----------------
__global__ __launch_bounds__(256) void edge_alpha4(const int* __restrict__ csr_src, const int* __restrict__ csr_dst,
                                                   const float* __restrict__ el4, const float* __restrict__ er4,
                                                   float* __restrict__ ex4, int E) {
  int t = blockIdx.x * 256 + threadIdx.x;
  if (t >= E) return;
  int s = csr_src[t], d = csr_dst[t];
  float4 l = *(const float4*)(el4 + (size_t)s * 4);
  float4 r = *(const float4*)(er4 + (size_t)d * 4);
  float4 o;
  o.x = __expf(lrelu(l.x + r.x));
  o.y = __expf(lrelu(l.y + r.y));
  o.z = __expf(lrelu(l.z + r.z));
  o.w = __expf(lrelu(l.w + r.w));
  *(float4*)(ex4 + (size_t)t * 4) = o;
}

__global__ __launch_bounds__(256) void edge_alpha1(const int* __restrict__ csr_src, const int* __restrict__ csr_dst,
                                                   const float* __restrict__ el1, const float* __restrict__ er1,
                                                   float* __restrict__ ex1, int E) {
  int t = blockIdx.x * 256 + threadIdx.x;
  if (t >= E) return;
  ex1[t] = __expf(lrelu(el1[csr_src[t]] + er1[csr_dst[t]]));
}

// ---------------- aggregation H=4: wave/node, dim-split 8B/lane gathers ----------------
// Epilogue: +res, elu (MODE1: double elu), rownorm; writes v*rn^-1 as bf16 + rnrm[n].
template <int MODE>
__global__ __launch_bounds__(256) void aggregate4(const unsigned short* __restrict__ featbf,
                                                  const float* __restrict__ ex4,
                                                  const int* __restrict__ csr_src,
                                                  const int* __restrict__ row_start,
                                                  const int* __restrict__ counts,
                                                  const float* __restrict__ res,
                                                  unsigned short* __restrict__ vbf,
                                                  float* __restrict__ rnrm, int Nn) {
  int n = (int)((blockIdx.x * blockDim.x + threadIdx.x) >> 6);
  if (n >= Nn) return;
  int lane = threadIdx.x & 63;
  int deg = counts[n], start = row_start[n];
  int slot = lane >> 2, h = lane & 3;
  // denom from contiguous ex reads
  float dsum = 0.f;
  for (int base = 0; base < deg; base += 16) {
    int i = base + slot;
    dsum += (i < deg) ? ex4[(size_t)(start + i) * 4 + h] : 0.f;
  }
#pragma unroll
  for (int off = 4; off < 64; off <<= 1) dsum += __shfl_xor(dsum, off);
  float inv = dsum > 0.f ? 1.f / dsum : 0.f;
  // accumulate
  int li = lane & 31, half = lane >> 5, hl = li >> 3;
  int dofs = li << 2;
  float a0 = 0.f, a1 = 0.f, a2 = 0.f, a3 = 0.f;
#define AGG4_STEP(t)                                                              \
  {                                                                               \
    int j = 2 * (t) + half;                                                       \
    int sj = __shfl(sv, j << 2);                                                  \
    float aw = __shfl(av, (j << 2) + hl);                                         \
    uint2 u = *(const uint2*)(featbf + ((size_t)sj << 7) + dofs);                 \
    a0 += aw * __uint_as_float(u.x << 16);                                        \
    a1 += aw * __uint_as_float(u.x & 0xffff0000u);                                \
    a2 += aw * __uint_as_float(u.y << 16);                                        \
    a3 += aw * __uint_as_float(u.y & 0xffff0000u);                                \
  }
  for (int base = 0; base < deg; base += 16) {
    int cnt = deg - base;
    cnt = cnt < 16 ? cnt : 16;
    int i = base + slot;
    bool vld = i < deg;
    int sv = vld ? csr_src[start + i] : 0;
    float av = vld ? ex4[(size_t)(start + i) * 4 + h] * inv : 0.f;
    if (cnt == 16) {
#pragma unroll
      for (int t = 0; t < 8; t++) AGG4_STEP(t)
    } else {
      int tmax = (cnt + 1) >> 1;
      for (int t = 0; t < tmax; t++) AGG4_STEP(t)
    }
  }
#undef AGG4_STEP
  a0 += __shfl_xor(a0, 32);
  a1 += __shfl_xor(a1, 32);
  a2 += __shfl_xor(a2, 32);
  a3 += __shfl_xor(a3, 32);
  float v0, v1, v2, v3;
  if (MODE == 1) {
    float4 rr = *(const float4*)(res + (size_t)n * 128 + dofs);
    v0 = elu1(elu1(a0 + rr.x));
    v1 = elu1(elu1(a1 + rr.y));
    v2 = elu1(elu1(a2 + rr.z));
    v3 = elu1(elu1(a3 + rr.w));
  } else {
    v0 = elu1(a0); v1 = elu1(a1); v2 = elu1(a2); v3 = elu1(a3);
  }
  float ss = v0 * v0 + v1 * v1 + v2 * v2 + v3 * v3;
#pragma unroll
  for (int off = 1; off < 32; off <<= 1) ss += __shfl_xor(ss, off);
  float rn = sqrtf(1e-6f + ss);
  float ri = 1.f / rn;
  if (lane < 32) {
    ushort4 pk;
    pk.x = f2bf(v0 * ri); pk.y = f2bf(v1 * ri); pk.z = f2bf(v2 * ri); pk.w = f2bf(v3 * ri);
    *(ushort4*)(vbf + (size_t)n * 128 + dofs) = pk;
  }
  if (lane == 0) rnrm[n] = rn;
}

// ---------------- aggregation H=1 (layer 2): fuses +res; writes out2[N][32] fp32 ----------------
__global__ __launch_bounds__(256) void aggregate1(const unsigned short* __restrict__ featbf,
                                                  const float* __restrict__ ex1,
                                                  const int* __restrict__ csr_src,
                                                  const int* __restrict__ row_start,
                                                  const int* __restrict__ counts,
                                                  const float* __restrict__ res2,
                                                  float* __restrict__ out2, int Nn) {
  int n = (int)((blockIdx.x * blockDim.x + threadIdx.x) >> 6);
  if (n >= Nn) return;
  int lane = threadIdx.x & 63;
  int deg = counts[n], start = row_start[n];
  float dsum = 0.f;
  for (int base = 0; base < deg; base += 64) {
    int i = base + lane;
    dsum += (i < deg) ? ex1[start + i] : 0.f;
  }
#pragma unroll
  for (int off = 1; off < 64; off <<= 1) dsum += __shfl_xor(dsum, off);
  float inv = dsum > 0.f ? 1.f / dsum : 0.f;
  int g = lane >> 3, dofs = (lane & 7) << 2;
  float a0 = 0.f, a1 = 0.f, a2 = 0.f, a3 = 0.f;
  for (int base = 0; base < deg; base += 32) {
    int cnt = deg - base;
    cnt = cnt < 32 ? cnt : 32;
    int i = base + (lane & 31);
    bool vld = i < deg;
    int sv = vld ? csr_src[start + i] : 0;
    float av = vld ? ex1[start + i] * inv : 0.f;
    int tmax = (cnt + 7) >> 3;
    for (int t = 0; t < tmax; t++) {
      int j = (t << 3) + g;
      int sj = __shfl(sv, j);
      float aw = __shfl(av, j);
      uint2 u = *(const uint2*)(featbf + ((size_t)sj << 5) + dofs);
      a0 += aw * __uint_as_float(u.x << 16);
      a1 += aw * __uint_as_float(u.x & 0xffff0000u);
      a2 += aw * __uint_as_float(u.y << 16);
      a3 += aw * __uint_as_float(u.y & 0xffff0000u);
    }
  }
#pragma unroll
  for (int off = 8; off < 64; off <<= 1) {
    a0 += __shfl_xor(a0, off);
    a1 += __shfl_xor(a1, off);
    a2 += __shfl_xor(a2, off);
    a3 += __shfl_xor(a3, off);
  }
  if (lane < 8) {
    float4 rr = *(const float4*)(res2 + (size_t)n * 32 + dofs);
    float4 o;
    o.x = a0 + rr.x; o.y = a1 + rr.y; o.z = a2 + rr.z; o.w = a3 + rr.w;
    *(float4*)(out2 + (size_t)n * 32 + dofs) = o;
  }
}

// ---------------- PairNorm finish: colsum over v = vbf*rn, then subtract colmean ----------------
__global__ __launch_bounds__(256) void colsum_k(const unsigned short* __restrict__ vbf,
                                                const float* __restrict__ rnrm,
                                                float* __restrict__ colsum, int Nn) {
  __shared__ float ls[256];
  int tid = threadIdx.x;
  int c = tid & 127, rsub = tid >> 7;
  float cs = 0.f;
  for (int r = blockIdx.x * 2 + rsub; r < Nn; r += gridDim.x * 2)
    cs += bf2f(vbf[(size_t)r * 128 + c]) * rnrm[r];
  ls[tid] = cs;
  __syncthreads();
  if (tid < 128) atomicAdd(&colsum[tid], ls[tid] + ls[tid + 128]);
}

__global__ __launch_bounds__(256) void sub_k(const unsigned short* __restrict__ vbf,
                                             const float* __restrict__ colsum,
                                             unsigned short* __restrict__ hbf, int Nn, float invN) {
  int t = blockIdx.x * 256 + threadIdx.x;   // one uint2 (4 cols) per thread
  if (t >= Nn * 32) return;
  int c4 = (t & 31) << 2;
  float4 m = *(const float4*)(colsum + c4);
  uint2 u = ((const uint2*)vbf)[t];
  unsigned int r0 = f2bf(__uint_as_float(u.x << 16) - m.x * invN);
  unsigned int r1 = f2bf(__uint_as_float(u.x & 0xffff0000u) - m.y * invN);
  unsigned int r2 = f2bf(__uint_as_float(u.y << 16) - m.z * invN);
  unsigned int r3 = f2bf(__uint_as_float(u.y & 0xffff0000u) - m.w * invN);
  uint2 o;
  o.x = r0 | (r1 << 16);
  o.y = r2 | (r3 << 16);
  ((uint2*)hbf)[t] = o;
}

// ---------------- final: mean over nodes of out2 ----------------
__global__ __launch_bounds__(256) void final_reduce(const float* __restrict__ out2,
                                                    float* __restrict__ outsum, int Nn) {
  __shared__ float ls[32];
  if (threadIdx.x < 32) ls[threadIdx.x] = 0.f;
  __syncthreads();
  int d = threadIdx.x & 31, rl = threadIdx.x >> 5;
  float acc = 0.f;
  for (int n = blockIdx.x * 8 + rl; n < Nn; n += gridDim.x * 8)
    acc += out2[(size_t)n * 32 + d];
  atomicAdd(&ls[d], acc);
  __syncthreads();
  if (threadIdx.x < 32) atomicAdd(&outsum[threadIdx.x], ls[threadIdx.x]);
}

__global__ void finalize_k(const float* __restrict__ outsum, float* __restrict__ out, float invN) {
  int t = threadIdx.x;
  if (t < 32) out[t] = outsum[t] * invN;
}

// ---------------- launcher ----------------
extern "C" void kernel_launch(void* const* d_in, const int* in_sizes, int n_in,
                              void* d_out, int out_size, void* d_ws, size_t ws_size,
                              hipStream_t stream) {
  const float* x     = (const float*)d_in[0];
  const int*   src   = (const int*)d_in[1];
  const int*   dst   = (const int*)d_in[2];
  const float* W0    = (const float*)d_in[3];
  const float* al0   = (const float*)d_in[4];
  const float* ar0   = (const float*)d_in[5];
  const float* W1    = (const float*)d_in[6];
  const float* al1   = (const float*)d_in[7];
  const float* ar1   = (const float*)d_in[8];
  const float* resW1 = (const float*)d_in[9];
  const float* W2    = (const float*)d_in[10];
  const float* al2   = (const float*)d_in[11];
  const float* ar2   = (const float*)d_in[12];
  const float* resW2 = (const float*)d_in[13];
  const int N = in_sizes[0] / 64;   // 100000
  const int E = in_sizes[1];        // 1600000
  const float invN = 1.f / (float)N;

  char* p = (char*)d_ws;
  auto alloc = [&](size_t bytes) { char* r = p; p += (bytes + 255) & ~(size_t)255; return r; };

  // zero-initialized region
  char* zbase = p;
  int*   counts  = (int*)alloc((size_t)4 * N);
  float* colsumA = (float*)alloc(512);
  float* colsumB = (float*)alloc(512);
  float* outsum  = (float*)alloc(128);
  size_t zbytes = (size_t)(p - zbase);

  int* row_start = (int*)alloc((size_t)4 * N);
  int* cursor    = (int*)alloc((size_t)4 * N);
  int* bsum      = (int*)alloc(512);
  int* csr_src   = (int*)alloc((size_t)4 * E);
  int* csr_dst   = (int*)alloc((size_t)4 * E);
  float* ex4     = (float*)alloc((size_t)16 * E);        // also ex1 for layer 2
  unsigned short* hbf    = (unsigned short*)alloc((size_t)2 * N * 128);
  unsigned short* featbf = (unsigned short*)alloc((size_t)2 * N * 128);
  unsigned short* vbf    = (unsigned short*)alloc((size_t)2 * N * 128);
  unsigned short* w0t = (unsigned short*)alloc((size_t)2 * 2 * 144 * 64);
  unsigned short* w1t = (unsigned short*)alloc((size_t)2 * 2 * 272 * 128);
  unsigned short* w2t = (unsigned short*)alloc((size_t)2 * 2 * 80 * 128);
  float* el4  = (float*)alloc((size_t)16 * N);
  float* er4  = (float*)alloc((size_t)16 * N);
  float* res  = (float*)alloc((size_t)4 * N * 128);      // layer-1 residual [N][128]
  float* rnrm = (float*)alloc((size_t)4 * N);
  float* res2 = res;                                     // layer-2 residual [N][32]
  float* out2 = res + (size_t)N * 32;                    // layer-2 output   [N][32]

  hipMemsetAsync(zbase, 0, zbytes, stream);

  // CSR build
  int eb = (E + 255) / 256;
  int nb1024 = (N + 1023) / 1024;
  hist_k<<<eb, 256, 0, stream>>>(dst, counts, E);
  scan1<<<nb1024, 256, 0, stream>>>(counts, row_start, bsum, N);
  scan2<<<1, 128, 0, stream>>>(bsum, nb1024);
  scan3<<<(N + 255) / 256, 256, 0, stream>>>(row_start, bsum, cursor, N);
  scatter_k<<<eb, 256, 0, stream>>>(src, dst, cursor, csr_src, csr_dst, E);

  // weights: [W | W@al | W@ar | pad | resW] transposed, bf16 hi+lo
  fill_pack<<<(144 * 64 + 255) / 256, 256, 0, stream>>>(W0, al0, ar0, nullptr, w0t, 64, 144, 128, 4, 144);
  fill_pack<<<(272 * 128 + 255) / 256, 256, 0, stream>>>(W1, al1, ar1, resW1, w1t, 128, 272, 128, 4, 144);
  fill_pack<<<(80 * 128 + 255) / 256, 256, 0, stream>>>(W2, al2, ar2, resW2, w2t, 128, 80, 32, 1, 48);
  cast_f2bf_k<<<(N * 64 + 255) / 256, 256, 0, stream>>>(x, hbf, N * 64);

  const int rowTiles = N / 16;                  // 6250, divisible by R=5
  const int gblocks = (rowTiles / 5 + 3) / 4;   // 1250 waves, 4/block
  const int aggblocks = (N + 3) / 4;            // wave per node

  // Layer 0
  gemm_bf16<64, 144, 5, 128, 4, 144><<<gblocks, 256, 0, stream>>>(hbf, w0t, featbf, el4, er4, nullptr, rowTiles);
  edge_alpha4<<<eb, 256, 0, stream>>>(csr_src, csr_dst, el4, er4, ex4, E);
  aggregate4<0><<<aggblocks, 256, 0, stream>>>(featbf, ex4, csr_src, row_start, counts, nullptr, vbf, rnrm, N);
  colsum_k<<<512, 256, 0, stream>>>(vbf, rnrm, colsumA, N);
  sub_k<<<(N * 32 + 255) / 256, 256, 0, stream>>>(vbf, colsumA, hbf, N, invN);

  // Layer 1
  gemm_bf16<128, 272, 5, 128, 4, 144><<<gblocks, 256, 0, stream>>>(hbf, w1t, featbf, el4, er4, res, rowTiles);
  edge_alpha4<<<eb, 256, 0, stream>>>(csr_src, csr_dst, el4, er4, ex4, E);
  aggregate4<1><<<aggblocks, 256, 0, stream>>>(featbf, ex4, csr_src, row_start, counts, res, vbf, rnrm, N);
  colsum_k<<<512, 256, 0, stream>>>(vbf, rnrm, colsumB, N);
  sub_k<<<(N * 32 + 255) / 256, 256, 0, stream>>>(vbf, colsumB, hbf, N, invN);

  // Layer 2
  gemm_bf16<128, 80, 5, 32, 1, 48><<<gblocks, 256, 0, stream>>>(hbf, w2t, featbf, el4, er4, res2, rowTiles);
  edge_alpha1<<<eb, 256, 0, stream>>>(csr_src, csr_dst, el4, er4, ex4, E);
  aggregate1<<<aggblocks, 256, 0, stream>>>(featbf, ex4, csr_src, row_start, counts, res2, out2, N);
  final_reduce<<<512, 256, 0, stream>>>(out2, outsum, N);
  finalize_k<<<1, 64, 0, stream>>>(outsum, (float*)d_out, invN);
}

// Round 4
// 781.984 us; speedup vs baseline: 1.5618x; 1.0189x over previous
//
#include <hip/hip_runtime.h>

// GAT 3-layer forward on MI355X — round 4.
// vs round 3: ELL-padded CSR (multiples of 16 -> branch-free fully-unrolled aggregation
// with unconditional next-chunk preload), single interleaved int2{src,dst} scatter
// (halves scatter write-allocate traffic), hbf aliased into ex4 to bound workspace.

typedef __attribute__((ext_vector_type(8))) short s8v;
typedef __attribute__((ext_vector_type(4))) float f4v;

__device__ __forceinline__ unsigned short f2bf(float f) {
  unsigned int x = __float_as_uint(f);
  x += 0x7fffu + ((x >> 16) & 1u);          // RTNE
  return (unsigned short)(x >> 16);
}
__device__ __forceinline__ float bf2f(unsigned short u) {
  return __uint_as_float(((unsigned int)u) << 16);
}
__device__ __forceinline__ float lrelu(float x) { return x > 0.f ? x : 0.2f * x; }
__device__ __forceinline__ float elu1(float x) { return x > 0.f ? x : expm1f(x); }

// ---------------- CSR build (padded to multiples of 16 per node) ----------------
__global__ __launch_bounds__(256) void hist_k(const int* __restrict__ dst, int* __restrict__ counts, int E) {
  int t = blockIdx.x * 256 + threadIdx.x;
  if (t < E) atomicAdd(&counts[dst[t]], 1);
}

__global__ __launch_bounds__(256) void scan1(const int* __restrict__ counts, int* __restrict__ rsp,
                                             int* __restrict__ bsum, int Nn) {
  __shared__ int s[256];
  int t = threadIdx.x;
  int base = blockIdx.x * 1024 + t * 4;
  int v0 = (base + 0 < Nn) ? ((counts[base + 0] + 15) & ~15) : 0;
  int v1 = (base + 1 < Nn) ? ((counts[base + 1] + 15) & ~15) : 0;
  int v2 = (base + 2 < Nn) ? ((counts[base + 2] + 15) & ~15) : 0;
  int v3 = (base + 3 < Nn) ? ((counts[base + 3] + 15) & ~15) : 0;
  s[t] = v0 + v1 + v2 + v3;
  __syncthreads();
  for (int off = 1; off < 256; off <<= 1) {
    int xv = (t >= off) ? s[t - off] : 0;
    __syncthreads();
    s[t] += xv;
    __syncthreads();
  }
  int excl = t ? s[t - 1] : 0;
  if (t == 255) bsum[blockIdx.x] = s[255];
  if (base + 0 < Nn) { rsp[base + 0] = excl; excl += v0; }
  if (base + 1 < Nn) { rsp[base + 1] = excl; excl += v1; }
  if (base + 2 < Nn) { rsp[base + 2] = excl; excl += v2; }
  if (base + 3 < Nn) { rsp[base + 3] = excl; }
}

__global__ __launch_bounds__(128) void scan2(int* __restrict__ bsum, int nb) {
  __shared__ int s[128];
  int t = threadIdx.x;
  s[t] = (t < nb) ? bsum[t] : 0;
  __syncthreads();
  for (int off = 1; off < 128; off <<= 1) {
    int xv = (t >= off) ? s[t - off] : 0;
    __syncthreads();
    s[t] += xv;
    __syncthreads();
  }
  if (t < nb) bsum[t] = t ? s[t - 1] : 0;
}

__global__ __launch_bounds__(256) void scan3(int* __restrict__ rsp, const int* __restrict__ bsum,
                                             int* __restrict__ cursor, int Nn) {
  int t = blockIdx.x * 256 + threadIdx.x;
  if (t < Nn) {
    int v = rsp[t] + bsum[t >> 10];
    rsp[t] = v;
    cursor[t] = v;
  }
}

__global__ __launch_bounds__(256) void scatter_k(const int* __restrict__ src, const int* __restrict__ dst,
                                                 int* __restrict__ cursor, int2* __restrict__ csr2, int E) {
  int t = blockIdx.x * 256 + threadIdx.x;
  if (t < E) {
    int d = dst[t];
    int pos = atomicAdd(&cursor[d], 1);
    int2 v; v.x = src[t]; v.y = d;
    csr2[pos] = v;                       // one 8B scattered store (one line/edge)
  }
}

// ---------------- fused weight pack: [W | W@al | W@ar | pad | resW], bf16 hi+lo ----------------
__global__ __launch_bounds__(256) void fill_pack(const float* __restrict__ W, const float* __restrict__ al,
                                                 const float* __restrict__ ar, const float* __restrict__ resW,
                                                 unsigned short* __restrict__ out,
                                                 int K, int M, int BF, int H, int RES0) {
  int t = blockIdx.x * 256 + threadIdx.x;
  if (t >= K * M) return;
  int c = t / K, k = t - c * K;
  float v = 0.f;
  if (c < BF) {
    v = W[k * BF + c];
  } else if (c < BF + H) {
    int h = c - BF;
    float s = 0.f;
    for (int d = 0; d < 32; d++) s += W[k * BF + h * 32 + d] * al[h * 32 + d];
    v = s;
  } else if (c < BF + 2 * H) {
    int h = c - BF - H;
    float s = 0.f;
    for (int d = 0; d < 32; d++) s += W[k * BF + h * 32 + d] * ar[h * 32 + d];
    v = s;
  } else if (c >= RES0) {
    v = resW[k * (M - RES0) + (c - RES0)];
  }
  unsigned short hi = f2bf(v);
  out[c * K + k] = hi;
  out[M * K + c * K + k] = f2bf(v - bf2f(hi));
}

__global__ __launch_bounds__(256) void cast_f2bf_k(const float* __restrict__ x, unsigned short* __restrict__ y, int n) {
  int t = blockIdx.x * 256 + threadIdx.x;
  if (t < n) y[t] = f2bf(x[t]);
}

// ---------------- GEMM: A[N,K](bf16) @ Bt[M,K](bf16 hi+lo) ----------------
template <int K, int M, int R, int BF, int H, int RES0>
__global__ __launch_bounds__(256) void gemm_bf16(const unsigned short* __restrict__ A,
                                                 const unsigned short* __restrict__ Bt,
                                                 unsigned short* __restrict__ featbf,
                                                 float* __restrict__ el, float* __restrict__ er,
                                                 float* __restrict__ res, int nRowTiles) {
  int wv = (int)((blockIdx.x * blockDim.x + threadIdx.x) >> 6);
  int tile0 = wv * R;
  if (tile0 >= nRowTiles) return;
  int lane = threadIdx.x & 63;
  int r = lane & 15, q = lane >> 4;
  s8v afrag[R][K / 32];
#pragma unroll
  for (int rr = 0; rr < R; rr++) {
    const unsigned short* arow = A + (size_t)((tile0 + rr) * 16 + r) * K + q * 8;
#pragma unroll
    for (int kk = 0; kk < K / 32; kk++) afrag[rr][kk] = *(const s8v*)(arow + kk * 32);
  }
#pragma unroll
  for (int ct = 0; ct < M / 16; ct++) {
    const unsigned short* brow = Bt + (size_t)(ct * 16 + r) * K + q * 8;
    s8v bhi[K / 32], blo[K / 32];
#pragma unroll
    for (int kk = 0; kk < K / 32; kk++) {
      bhi[kk] = *(const s8v*)(brow + kk * 32);
      blo[kk] = *(const s8v*)(brow + (size_t)M * K + kk * 32);
    }
    int col = ct * 16 + r;
#pragma unroll
    for (int rr = 0; rr < R; rr++) {
      f4v acc = {0.f, 0.f, 0.f, 0.f};
#pragma unroll
      for (int kk = 0; kk < K / 32; kk++) {
        acc = __builtin_amdgcn_mfma_f32_16x16x32_bf16(afrag[rr][kk], bhi[kk], acc, 0, 0, 0);
        acc = __builtin_amdgcn_mfma_f32_16x16x32_bf16(afrag[rr][kk], blo[kk], acc, 0, 0, 0);
      }
      int row0 = (tile0 + rr) * 16 + q * 4;
#pragma unroll
      for (int i = 0; i < 4; i++) {
        float v = acc[i];
        size_t row = (size_t)(row0 + i);
        if (col < BF) {
          featbf[row * BF + col] = f2bf(v);
        } else if (col < BF + H) {
          el[row * H + (col - BF)] = v;
        } else if (col < BF + 2 * H) {
          er[row * H + (col - BF - H)] = v;
        } else if (RES0 < M && col >= RES0) {
          res[row * (M - RES0) + (col - RES0)] = v;
        }
      }
    }
  }
}

// ---------------- edge-parallel exp over PADDED slots (pads: dst<0 -> ex=0) ----------------
__global__ __launch_bounds__(256) void edge_alpha4(const int2* __restrict__ csr2,
                                                   const float* __restrict__ el4, const float* __restrict__ er4,
                                                   float* __restrict__ ex4, int Emax) {
  int t = blockIdx.x * 256 + threadIdx.x;
  if (t >= Emax) return;
  int2 sd = csr2[t];
  float4 o = {0.f, 0.f, 0.f, 0.f};
  if (sd.y >= 0) {
    float4 l = *(const float4*)(el4 + (size_t)sd.x * 4);
    float4 r = *(const float4*)(er4 + (size_t)sd.y * 4);
    o.x = __expf(lrelu(l.x + r.x));
    o.y = __expf(lrelu(l.y + r.y));
    o.z = __expf(lrelu(l.z + r.z));
    o.w = __expf(lrelu(l.w + r.w));
  }
  *(float4*)(ex4 + (size_t)t * 4) = o;
}

__global__ __launch_bounds__(256) void edge_alpha1(const int2* __restrict__ csr2,
                                                   const float* __restrict__ el1, const float* __restrict__ er1,
                                                   float* __restrict__ ex1, int Emax) {
  int t = blockIdx.x * 256 + threadIdx.x;
  if (t >= Emax) return;
  int2 sd = csr2[t];
  ex1[t] = (sd.y >= 0) ? __expf(lrelu(el1[sd.x] + er1[sd.y])) : 0.f;
}

// ---------------- aggregation H=4: branch-free padded chunks of 16, preloaded ----------------
template <int MODE>
__global__ __launch_bounds__(256) void aggregate4(const unsigned short* __restrict__ featbf,
                                                  const float* __restrict__ ex4,
                                                  const int2* __restrict__ csr2,
                                                  const int* __restrict__ rsp,
                                                  const int* __restrict__ counts,
                                                  const float* __restrict__ res,
                                                  unsigned short* __restrict__ vbf,
                                                  float* __restrict__ rnrm, int Nn) {
  int n = (int)((blockIdx.x * blockDim.x + threadIdx.x) >> 6);
  if (n >= Nn) return;
  int lane = threadIdx.x & 63;
  int deg = counts[n], start = rsp[n];
  int chunks = (deg + 15) >> 4;
  int slot = lane >> 2, h = lane & 3;
  const float* exb = ex4 + (size_t)(start + slot) * 4 + h;
  // denom: pads are zero, no masking
  float dsum = 0.f;
  {
    float cur = exb[0];
    for (int c = 1; c < chunks; c++) {
      float nxt = exb[(size_t)c * 64];
      dsum += cur;
      cur = nxt;
    }
    if (chunks > 0) dsum += cur;
  }
#pragma unroll
  for (int off = 4; off < 64; off <<= 1) dsum += __shfl_xor(dsum, off);
  float inv = dsum > 0.f ? 1.f / dsum : 0.f;
  // accumulate: fully unrolled 8 steps per 16-edge chunk, preload next chunk
  int li = lane & 31, half = lane >> 5, hl = li >> 3;
  int dofs = li << 2;
  float a0 = 0.f, a1 = 0.f, a2 = 0.f, a3 = 0.f;
  const int2* cs = csr2 + start + slot;
  int sv = cs[0].x;
  float av = exb[0];
  for (int c = 0; c < chunks; c++) {
    int nsv = cs[(size_t)(c + 1) * 16].x;        // tail margin allocated
    float nav = exb[(size_t)(c + 1) * 64];
    float aw_all = av * inv;
#pragma unroll
    for (int t = 0; t < 8; t++) {
      int j = 2 * t + half;
      int sj = __shfl(sv, j << 2);
      float aw = __shfl(aw_all, (j << 2) + hl);
      sj = sj > 0 ? sj : 0;                      // pad src=-1 -> 0 (aw=0)
      uint2 u = *(const uint2*)(featbf + ((size_t)sj << 7) + dofs);
      a0 += aw * __uint_as_float(u.x << 16);
      a1 += aw * __uint_as_float(u.x & 0xffff0000u);
      a2 += aw * __uint_as_float(u.y << 16);
      a3 += aw * __uint_as_float(u.y & 0xffff0000u);
    }
    sv = nsv;
    av = nav;
  }
  a0 += __shfl_xor(a0, 32);
  a1 += __shfl_xor(a1, 32);
  a2 += __shfl_xor(a2, 32);
  a3 += __shfl_xor(a3, 32);
  float v0, v1, v2, v3;
  if (MODE == 1) {
    float4 rr = *(const float4*)(res + (size_t)n * 128 + dofs);
    v0 = elu1(elu1(a0 + rr.x));
    v1 = elu1(elu1(a1 + rr.y));
    v2 = elu1(elu1(a2 + rr.z));
    v3 = elu1(elu1(a3 + rr.w));
  } else {
    v0 = elu1(a0); v1 = elu1(a1); v2 = elu1(a2); v3 = elu1(a3);
  }
  float ss = v0 * v0 + v1 * v1 + v2 * v2 + v3 * v3;
#pragma unroll
  for (int off = 1; off < 32; off <<= 1) ss += __shfl_xor(ss, off);
  float rn = sqrtf(1e-6f + ss);
  float ri = 1.f / rn;
  if (lane < 32) {
    ushort4 pk;
    pk.x = f2bf(v0 * ri); pk.y = f2bf(v1 * ri); pk.z = f2bf(v2 * ri); pk.w = f2bf(v3 * ri);
    *(ushort4*)(vbf + (size_t)n * 128 + dofs) = pk;
  }
  if (lane == 0) rnrm[n] = rn;
}

// ---------------- aggregation H=1 (layer 2): padded chunks of 16 ----------------
__global__ __launch_bounds__(256) void aggregate1(const unsigned short* __restrict__ featbf,
                                                  const float* __restrict__ ex1,
                                                  const int2* __restrict__ csr2,
                                                  const int* __restrict__ rsp,
                                                  const int* __restrict__ counts,
                                                  const float* __restrict__ res2,
                                                  float* __restrict__ out2, int Nn) {
  int n = (int)((blockIdx.x * blockDim.x + threadIdx.x) >> 6);
  if (n >= Nn) return;
  int lane = threadIdx.x & 63;
  int deg = counts[n], start = rsp[n];
  int chunks = (deg + 15) >> 4;
  int l16 = lane & 15;
  const float* exb = ex1 + start + l16;
  float dsum = 0.f;
  {
    float cur = exb[0];
    for (int c = 1; c < chunks; c++) {
      float nxt = exb[(size_t)c * 16];
      dsum += cur;
      cur = nxt;
    }
    if (chunks > 0) dsum += cur;
  }
#pragma unroll
  for (int off = 1; off < 16; off <<= 1) dsum += __shfl_xor(dsum, off);
  float inv = dsum > 0.f ? 1.f / dsum : 0.f;
  int g = lane >> 3, dofs = (lane & 7) << 2;
  const int2* cs = csr2 + start + l16;
  int sv = cs[0].x;
  float av = exb[0];
  float a0 = 0.f, a1 = 0.f, a2 = 0.f, a3 = 0.f;
  for (int c = 0; c < chunks; c++) {
    int nsv = cs[(size_t)(c + 1) * 16].x;
    float nav = exb[(size_t)(c + 1) * 16];
    float aw_all = av * inv;
#pragma unroll
    for (int t = 0; t < 2; t++) {
      int j = (t << 3) + g;
      int sj = __shfl(sv, j);
      float aw = __shfl(aw_all, j);
      sj = sj > 0 ? sj : 0;
      uint2 u = *(const uint2*)(featbf + ((size_t)sj << 5) + dofs);
      a0 += aw * __uint_as_float(u.x << 16);
      a1 += aw * __uint_as_float(u.x & 0xffff0000u);
      a2 += aw * __uint_as_float(u.y << 16);
      a3 += aw * __uint_as_float(u.y & 0xffff0000u);
    }
    sv = nsv;
    av = nav;
  }
#pragma unroll
  for (int off = 8; off < 64; off <<= 1) {
    a0 += __shfl_xor(a0, off);
    a1 += __shfl_xor(a1, off);
    a2 += __shfl_xor(a2, off);
    a3 += __shfl_xor(a3, off);
  }
  if (lane < 8) {
    float4 rr = *(const float4*)(res2 + (size_t)n * 32 + dofs);
    float4 o;
    o.x = a0 + rr.x; o.y = a1 + rr.y; o.z = a2 + rr.z; o.w = a3 + rr.w;
    *(float4*)(out2 + (size_t)n * 32 + dofs) = o;
  }
}

// ---------------- PairNorm finish ----------------
__global__ __launch_bounds__(256) void colsum_k(const unsigned short* __restrict__ vbf,
                                                const float* __restrict__ rnrm,
                                                float* __restrict__ colsum, int Nn) {
  __shared__ float ls[256];
  int tid = threadIdx.x;
  int c = tid & 127, rsub = tid >> 7;
  float cs = 0.f;
  for (int r = blockIdx.x * 2 + rsub; r < Nn; r += gridDim.x * 2)
    cs += bf2f(vbf[(size_t)r * 128 + c]) * rnrm[r];
  ls[tid] = cs;
  __syncthreads();
  if (tid < 128) atomicAdd(&colsum[tid], ls[tid] + ls[tid + 128]);
}

__global__ __launch_bounds__(256) void sub_k(const unsigned short* __restrict__ vbf,
                                             const float* __restrict__ colsum,
                                             unsigned short* __restrict__ hbf, int Nn, float invN) {
  int t = blockIdx.x * 256 + threadIdx.x;   // one uint2 (4 cols) per thread
  if (t >= Nn * 32) return;
  int c4 = (t & 31) << 2;
  float4 m = *(const float4*)(colsum + c4);
  uint2 u = ((const uint2*)vbf)[t];
  unsigned int r0 = f2bf(__uint_as_float(u.x << 16) - m.x * invN);
  unsigned int r1 = f2bf(__uint_as_float(u.x & 0xffff0000u) - m.y * invN);
  unsigned int r2 = f2bf(__uint_as_float(u.y << 16) - m.z * invN);
  unsigned int r3 = f2bf(__uint_as_float(u.y & 0xffff0000u) - m.w * invN);
  uint2 o;
  o.x = r0 | (r1 << 16);
  o.y = r2 | (r3 << 16);
  ((uint2*)hbf)[t] = o;
}

// ---------------- final: mean over nodes of out2 ----------------
__global__ __launch_bounds__(256) void final_reduce(const float* __restrict__ out2,
                                                    float* __restrict__ outsum, int Nn) {
  __shared__ float ls[32];
  if (threadIdx.x < 32) ls[threadIdx.x] = 0.f;
  __syncthreads();
  int d = threadIdx.x & 31, rl = threadIdx.x >> 5;
  float acc = 0.f;
  for (int n = blockIdx.x * 8 + rl; n < Nn; n += gridDim.x * 8)
    acc += out2[(size_t)n * 32 + d];
  atomicAdd(&ls[d], acc);
  __syncthreads();
  if (threadIdx.x < 32) atomicAdd(&outsum[threadIdx.x], ls[threadIdx.x]);
}

__global__ void finalize_k(const float* __restrict__ outsum, float* __restrict__ out, float invN) {
  int t = threadIdx.x;
  if (t < 32) out[t] = outsum[t] * invN;
}

// ---------------- launcher ----------------
extern "C" void kernel_launch(void* const* d_in, const int* in_sizes, int n_in,
                              void* d_out, int out_size, void* d_ws, size_t ws_size,
                              hipStream_t stream) {
  const float* x     = (const float*)d_in[0];
  const int*   src   = (const int*)d_in[1];
  const int*   dst   = (const int*)d_in[2];
  const float* W0    = (const float*)d_in[3];
  const float* al0   = (const float*)d_in[4];
  const float* ar0   = (const float*)d_in[5];
  const float* W1    = (const float*)d_in[6];
  const float* al1   = (const float*)d_in[7];
  const float* ar1   = (const float*)d_in[8];
  const float* resW1 = (const float*)d_in[9];
  const float* W2    = (const float*)d_in[10];
  const float* al2   = (const float*)d_in[11];
  const float* ar2   = (const float*)d_in[12];
  const float* resW2 = (const float*)d_in[13];
  const int N = in_sizes[0] / 64;   // 100000
  const int E = in_sizes[1];        // 1600000
  const float invN = 1.f / (float)N;
  const int Emax = E + 15 * N + 1024;   // hard upper bound on padded slot count + margin

  char* p = (char*)d_ws;
  auto alloc = [&](size_t bytes) { char* r = p; p += (bytes + 255) & ~(size_t)255; return r; };

  // zero-initialized region
  char* zbase = p;
  int*   counts  = (int*)alloc((size_t)4 * N);
  float* colsumA = (float*)alloc(512);
  float* colsumB = (float*)alloc(512);
  float* outsum  = (float*)alloc(128);
  size_t zbytes = (size_t)(p - zbase);

  int* rsp    = (int*)alloc((size_t)4 * N);     // padded row starts
  int* cursor = (int*)alloc((size_t)4 * N);
  int* bsum   = (int*)alloc(512);
  int2* csr2  = (int2*)alloc((size_t)8 * Emax);     // memset 0xFF: pads {-1,-1}
  float* ex4  = (float*)alloc((size_t)16 * Emax);   // also ex1; hbf aliases its head
  unsigned short* hbf = (unsigned short*)ex4;       // safe: gemm_k reads hbf before alpha_k writes ex4
  unsigned short* featbf = (unsigned short*)alloc((size_t)2 * N * 128);
  unsigned short* vbf    = (unsigned short*)alloc((size_t)2 * N * 128);
  unsigned short* w0t = (unsigned short*)alloc((size_t)2 * 2 * 144 * 64);
  unsigned short* w1t = (unsigned short*)alloc((size_t)2 * 2 * 272 * 128);
  unsigned short* w2t = (unsigned short*)alloc((size_t)2 * 2 * 80 * 128);
  float* el4  = (float*)alloc((size_t)16 * N);
  float* er4  = (float*)alloc((size_t)16 * N);
  float* res  = (float*)alloc((size_t)4 * N * 128);  // layer-1 residual [N][128]
  float* rnrm = (float*)alloc((size_t)4 * N);
  float* res2 = res;                                 // layer-2 residual [N][32]
  float* out2 = res + (size_t)N * 32;                // layer-2 output   [N][32]

  hipMemsetAsync(zbase, 0, zbytes, stream);
  hipMemsetAsync(csr2, 0xFF, (size_t)8 * Emax, stream);

  // CSR build (padded)
  int eb = (E + 255) / 256;
  int aeb = (Emax + 255) / 256;
  int nb1024 = (N + 1023) / 1024;
  hist_k<<<eb, 256, 0, stream>>>(dst, counts, E);
  scan1<<<nb1024, 256, 0, stream>>>(counts, rsp, bsum, N);
  scan2<<<1, 128, 0, stream>>>(bsum, nb1024);
  scan3<<<(N + 255) / 256, 256, 0, stream>>>(rsp, bsum, cursor, N);
  scatter_k<<<eb, 256, 0, stream>>>(src, dst, cursor, csr2, E);

  // weights: [W | W@al | W@ar | pad | resW] transposed, bf16 hi+lo; input cast
  fill_pack<<<(144 * 64 + 255) / 256, 256, 0, stream>>>(W0, al0, ar0, nullptr, w0t, 64, 144, 128, 4, 144);
  fill_pack<<<(272 * 128 + 255) / 256, 256, 0, stream>>>(W1, al1, ar1, resW1, w1t, 128, 272, 128, 4, 144);
  fill_pack<<<(80 * 128 + 255) / 256, 256, 0, stream>>>(W2, al2, ar2, resW2, w2t, 128, 80, 32, 1, 48);
  cast_f2bf_k<<<(N * 64 + 255) / 256, 256, 0, stream>>>(x, hbf, N * 64);

  const int rowTiles = N / 16;                  // 6250, divisible by R=5
  const int gblocks = (rowTiles / 5 + 3) / 4;   // 1250 waves, 4/block
  const int aggblocks = (N + 3) / 4;            // wave per node

  // Layer 0
  gemm_bf16<64, 144, 5, 128, 4, 144><<<gblocks, 256, 0, stream>>>(hbf, w0t, featbf, el4, er4, nullptr, rowTiles);
  edge_alpha4<<<aeb, 256, 0, stream>>>(csr2, el4, er4, ex4, Emax);
  aggregate4<0><<<aggblocks, 256, 0, stream>>>(featbf, ex4, csr2, rsp, counts, nullptr, vbf, rnrm, N);
  colsum_k<<<512, 256, 0, stream>>>(vbf, rnrm, colsumA, N);
  sub_k<<<(N * 32 + 255) / 256, 256, 0, stream>>>(vbf, colsumA, hbf, N, invN);

  // Layer 1
  gemm_bf16<128, 272, 5, 128, 4, 144><<<gblocks, 256, 0, stream>>>(hbf, w1t, featbf, el4, er4, res, rowTiles);
  edge_alpha4<<<aeb, 256, 0, stream>>>(csr2, el4, er4, ex4, Emax);
  aggregate4<1><<<aggblocks, 256, 0, stream>>>(featbf, ex4, csr2, rsp, counts, res, vbf, rnrm, N);
  colsum_k<<<512, 256, 0, stream>>>(vbf, rnrm, colsumB, N);
  sub_k<<<(N * 32 + 255) / 256, 256, 0, stream>>>(vbf, colsumB, hbf, N, invN);

  // Layer 2
  gemm_bf16<128, 80, 5, 32, 1, 48><<<gblocks, 256, 0, stream>>>(hbf, w2t, featbf, el4, er4, res2, rowTiles);
  edge_alpha1<<<aeb, 256, 0, stream>>>(csr2, el4, er4, ex4, Emax);
  aggregate1<<<aggblocks, 256, 0, stream>>>(featbf, ex4, csr2, rsp, counts, res2, out2, N);
  final_reduce<<<512, 256, 0, stream>>>(out2, outsum, N);
  finalize_k<<<1, 64, 0, stream>>>(outsum, (float*)d_out, invN);
}

// Round 5
// 750.282 us; speedup vs baseline: 1.6278x; 1.0423x over previous
//
#include <hip/hip_runtime.h>

// GAT 3-layer forward on MI355X — round 5.
// vs round 4: csr stores src only (4B/edge; alpha pass is node-parallel and needs no
// stored dst), scatter is dst-range-partitioned into 8 passes so the active write
// region (~1.6MB) fits each XCD's L2 (kills the 4x write-allocate thrash seen in R4:
// WRITE_SIZE 99.5MB for a 25MB array).

typedef __attribute__((ext_vector_type(8))) short s8v;
typedef __attribute__((ext_vector_type(4))) float f4v;

__device__ __forceinline__ unsigned short f2bf(float f) {
  unsigned int x = __float_as_uint(f);
  x += 0x7fffu + ((x >> 16) & 1u);          // RTNE
  return (unsigned short)(x >> 16);
}
__device__ __forceinline__ float bf2f(unsigned short u) {
  return __uint_as_float(((unsigned int)u) << 16);
}
__device__ __forceinline__ float lrelu(float x) { return x > 0.f ? x : 0.2f * x; }
__device__ __forceinline__ float elu1(float x) { return x > 0.f ? x : expm1f(x); }

// ---------------- CSR build (padded to multiples of 16 per node) ----------------
__global__ __launch_bounds__(256) void hist_k(const int* __restrict__ dst, int* __restrict__ counts, int E) {
  int t = blockIdx.x * 256 + threadIdx.x;
  if (t < E) atomicAdd(&counts[dst[t]], 1);
}

__global__ __launch_bounds__(256) void scan1(const int* __restrict__ counts, int* __restrict__ rsp,
                                             int* __restrict__ bsum, int Nn) {
  __shared__ int s[256];
  int t = threadIdx.x;
  int base = blockIdx.x * 1024 + t * 4;
  int v0 = (base + 0 < Nn) ? ((counts[base + 0] + 15) & ~15) : 0;
  int v1 = (base + 1 < Nn) ? ((counts[base + 1] + 15) & ~15) : 0;
  int v2 = (base + 2 < Nn) ? ((counts[base + 2] + 15) & ~15) : 0;
  int v3 = (base + 3 < Nn) ? ((counts[base + 3] + 15) & ~15) : 0;
  s[t] = v0 + v1 + v2 + v3;
  __syncthreads();
  for (int off = 1; off < 256; off <<= 1) {
    int xv = (t >= off) ? s[t - off] : 0;
    __syncthreads();
    s[t] += xv;
    __syncthreads();
  }
  int excl = t ? s[t - 1] : 0;
  if (t == 255) bsum[blockIdx.x] = s[255];
  if (base + 0 < Nn) { rsp[base + 0] = excl; excl += v0; }
  if (base + 1 < Nn) { rsp[base + 1] = excl; excl += v1; }
  if (base + 2 < Nn) { rsp[base + 2] = excl; excl += v2; }
  if (base + 3 < Nn) { rsp[base + 3] = excl; }
}

__global__ __launch_bounds__(128) void scan2(int* __restrict__ bsum, int nb) {
  __shared__ int s[128];
  int t = threadIdx.x;
  s[t] = (t < nb) ? bsum[t] : 0;
  __syncthreads();
  for (int off = 1; off < 128; off <<= 1) {
    int xv = (t >= off) ? s[t - off] : 0;
    __syncthreads();
    s[t] += xv;
    __syncthreads();
  }
  if (t < nb) bsum[t] = t ? s[t - 1] : 0;
}

__global__ __launch_bounds__(256) void scan3(int* __restrict__ rsp, const int* __restrict__ bsum,
                                             int* __restrict__ cursor, int Nn) {
  int t = blockIdx.x * 256 + threadIdx.x;
  if (t < Nn) {
    int v = rsp[t] + bsum[t >> 10];
    rsp[t] = v;
    cursor[t] = v;
  }
}

// dst-range-partitioned scatter: pass p handles dst>>shift == p; active write region
// per pass ~csr_src/8 (~1.6MB) -> XCD-L2-resident, full-line dirty evictions.
__global__ __launch_bounds__(256) void pscatter_k(const int* __restrict__ src, const int* __restrict__ dst,
                                                  int* __restrict__ cursor, int* __restrict__ csr_src,
                                                  int E, int shift) {
  int tid = blockIdx.x * 256 + threadIdx.x;
  int stride = gridDim.x * 256;
  for (int p = 0; p < 8; p++) {
    for (int e = tid; e < E; e += stride) {
      int d = dst[e];
      if ((d >> shift) == p) {
        int pos = atomicAdd(&cursor[d], 1);
        csr_src[pos] = src[e];
      }
    }
  }
}

// ---------------- fused weight pack: [W | W@al | W@ar | pad | resW], bf16 hi+lo ----------------
__global__ __launch_bounds__(256) void fill_pack(const float* __restrict__ W, const float* __restrict__ al,
                                                 const float* __restrict__ ar, const float* __restrict__ resW,
                                                 unsigned short* __restrict__ out,
                                                 int K, int M, int BF, int H, int RES0) {
  int t = blockIdx.x * 256 + threadIdx.x;
  if (t >= K * M) return;
  int c = t / K, k = t - c * K;
  float v = 0.f;
  if (c < BF) {
    v = W[k * BF + c];
  } else if (c < BF + H) {
    int h = c - BF;
    float s = 0.f;
    for (int d = 0; d < 32; d++) s += W[k * BF + h * 32 + d] * al[h * 32 + d];
    v = s;
  } else if (c < BF + 2 * H) {
    int h = c - BF - H;
    float s = 0.f;
    for (int d = 0; d < 32; d++) s += W[k * BF + h * 32 + d] * ar[h * 32 + d];
    v = s;
  } else if (c >= RES0) {
    v = resW[k * (M - RES0) + (c - RES0)];
  }
  unsigned short hi = f2bf(v);
  out[c * K + k] = hi;
  out[M * K + c * K + k] = f2bf(v - bf2f(hi));
}

__global__ __launch_bounds__(256) void cast_f2bf_k(const float* __restrict__ x, unsigned short* __restrict__ y, int n) {
  int t = blockIdx.x * 256 + threadIdx.x;
  if (t < n) y[t] = f2bf(x[t]);
}

// ---------------- GEMM: A[N,K](bf16) @ Bt[M,K](bf16 hi+lo) ----------------
template <int K, int M, int R, int BF, int H, int RES0>
__global__ __launch_bounds__(256) void gemm_bf16(const unsigned short* __restrict__ A,
                                                 const unsigned short* __restrict__ Bt,
                                                 unsigned short* __restrict__ featbf,
                                                 float* __restrict__ el, float* __restrict__ er,
                                                 float* __restrict__ res, int nRowTiles) {
  int wv = (int)((blockIdx.x * blockDim.x + threadIdx.x) >> 6);
  int tile0 = wv * R;
  if (tile0 >= nRowTiles) return;
  int lane = threadIdx.x & 63;
  int r = lane & 15, q = lane >> 4;
  s8v afrag[R][K / 32];
#pragma unroll
  for (int rr = 0; rr < R; rr++) {
    const unsigned short* arow = A + (size_t)((tile0 + rr) * 16 + r) * K + q * 8;
#pragma unroll
    for (int kk = 0; kk < K / 32; kk++) afrag[rr][kk] = *(const s8v*)(arow + kk * 32);
  }
#pragma unroll
  for (int ct = 0; ct < M / 16; ct++) {
    const unsigned short* brow = Bt + (size_t)(ct * 16 + r) * K + q * 8;
    s8v bhi[K / 32], blo[K / 32];
#pragma unroll
    for (int kk = 0; kk < K / 32; kk++) {
      bhi[kk] = *(const s8v*)(brow + kk * 32);
      blo[kk] = *(const s8v*)(brow + (size_t)M * K + kk * 32);
    }
    int col = ct * 16 + r;
#pragma unroll
    for (int rr = 0; rr < R; rr++) {
      f4v acc = {0.f, 0.f, 0.f, 0.f};
#pragma unroll
      for (int kk = 0; kk < K / 32; kk++) {
        acc = __builtin_amdgcn_mfma_f32_16x16x32_bf16(afrag[rr][kk], bhi[kk], acc, 0, 0, 0);
        acc = __builtin_amdgcn_mfma_f32_16x16x32_bf16(afrag[rr][kk], blo[kk], acc, 0, 0, 0);
      }
      int row0 = (tile0 + rr) * 16 + q * 4;
#pragma unroll
      for (int i = 0; i < 4; i++) {
        float v = acc[i];
        size_t row = (size_t)(row0 + i);
        if (col < BF) {
          featbf[row * BF + col] = f2bf(v);
        } else if (col < BF + H) {
          el[row * H + (col - BF)] = v;
        } else if (col < BF + 2 * H) {
          er[row * H + (col - BF - H)] = v;
        } else if (RES0 < M && col >= RES0) {
          res[row * (M - RES0) + (col - RES0)] = v;
        }
      }
    }
  }
}

// ---------------- node-parallel alpha: wave/node, writes ex contiguously ----------------
__global__ __launch_bounds__(256) void alpha4_k(const int* __restrict__ csr_src,
                                                const float* __restrict__ el4, const float* __restrict__ er4,
                                                float* __restrict__ ex4,
                                                const int* __restrict__ rsp, const int* __restrict__ counts,
                                                int Nn) {
  int n = (int)((blockIdx.x * blockDim.x + threadIdx.x) >> 6);
  if (n >= Nn) return;
  int lane = threadIdx.x & 63;
  int deg = counts[n], start = rsp[n];
  int chunks = (deg + 15) >> 4;
  int slot = lane >> 2, h = lane & 3;
  float ern = er4[n * 4 + h];
  int base = start + slot;
  for (int c = 0; c < chunks; c++) {
    int s = csr_src[base + c * 16];
    float v = 0.f;
    if (s >= 0) v = __expf(lrelu(el4[(size_t)s * 4 + h] + ern));
    ex4[(size_t)(base + c * 16) * 4 + h] = v;
  }
}

__global__ __launch_bounds__(256) void alpha1_k(const int* __restrict__ csr_src,
                                                const float* __restrict__ el1, const float* __restrict__ er1,
                                                float* __restrict__ ex1,
                                                const int* __restrict__ rsp, const int* __restrict__ counts,
                                                int Nn) {
  int n = (int)((blockIdx.x * blockDim.x + threadIdx.x) >> 6);
  if (n >= Nn) return;
  int lane = threadIdx.x & 63;
  int deg = counts[n], start = rsp[n];
  int tot = ((deg + 15) >> 4) << 4;
  float ern = er1[n];
  for (int i = lane; i < tot; i += 64) {
    int s = csr_src[start + i];
    ex1[start + i] = (s >= 0) ? __expf(lrelu(el1[s] + ern)) : 0.f;
  }
}

// ---------------- aggregation H=4: branch-free padded chunks of 16, preloaded ----------------
template <int MODE>
__global__ __launch_bounds__(256) void aggregate4(const unsigned short* __restrict__ featbf,
                                                  const float* __restrict__ ex4,
                                                  const int* __restrict__ csr_src,
                                                  const int* __restrict__ rsp,
                                                  const int* __restrict__ counts,
                                                  const float* __restrict__ res,
                                                  unsigned short* __restrict__ vbf,
                                                  float* __restrict__ rnrm, int Nn) {
  int n = (int)((blockIdx.x * blockDim.x + threadIdx.x) >> 6);
  if (n >= Nn) return;
  int lane = threadIdx.x & 63;
  int deg = counts[n], start = rsp[n];
  int chunks = (deg + 15) >> 4;
  int slot = lane >> 2, h = lane & 3;
  const float* exb = ex4 + (size_t)(start + slot) * 4 + h;
  // denom: pads are zero, no masking
  float dsum = 0.f;
  {
    float cur = exb[0];
    for (int c = 1; c < chunks; c++) {
      float nxt = exb[(size_t)c * 64];
      dsum += cur;
      cur = nxt;
    }
    if (chunks > 0) dsum += cur;
  }
#pragma unroll
  for (int off = 4; off < 64; off <<= 1) dsum += __shfl_xor(dsum, off);
  float inv = dsum > 0.f ? 1.f / dsum : 0.f;
  // accumulate: fully unrolled 8 steps per 16-edge chunk, preload next chunk
  int li = lane & 31, half = lane >> 5, hl = li >> 3;
  int dofs = li << 2;
  float a0 = 0.f, a1 = 0.f, a2 = 0.f, a3 = 0.f;
  const int* cs = csr_src + start + slot;
  int sv = cs[0];
  float av = exb[0];
  for (int c = 0; c < chunks; c++) {
    int nsv = cs[(size_t)(c + 1) * 16];          // tail margin allocated
    float nav = exb[(size_t)(c + 1) * 64];
    float aw_all = av * inv;
#pragma unroll
    for (int t = 0; t < 8; t++) {
      int j = 2 * t + half;
      int sj = __shfl(sv, j << 2);
      float aw = __shfl(aw_all, (j << 2) + hl);
      sj = sj > 0 ? sj : 0;                      // pad src=-1 -> 0 (aw=0)
      uint2 u = *(const uint2*)(featbf + ((size_t)sj << 7) + dofs);
      a0 += aw * __uint_as_float(u.x << 16);
      a1 += aw * __uint_as_float(u.x & 0xffff0000u);
      a2 += aw * __uint_as_float(u.y << 16);
      a3 += aw * __uint_as_float(u.y & 0xffff0000u);
    }
    sv = nsv;
    av = nav;
  }
  a0 += __shfl_xor(a0, 32);
  a1 += __shfl_xor(a1, 32);
  a2 += __shfl_xor(a2, 32);
  a3 += __shfl_xor(a3, 32);
  float v0, v1, v2, v3;
  if (MODE == 1) {
    float4 rr = *(const float4*)(res + (size_t)n * 128 + dofs);
    v0 = elu1(elu1(a0 + rr.x));
    v1 = elu1(elu1(a1 + rr.y));
    v2 = elu1(elu1(a2 + rr.z));
    v3 = elu1(elu1(a3 + rr.w));
  } else {
    v0 = elu1(a0); v1 = elu1(a1); v2 = elu1(a2); v3 = elu1(a3);
  }
  float ss = v0 * v0 + v1 * v1 + v2 * v2 + v3 * v3;
#pragma unroll
  for (int off = 1; off < 32; off <<= 1) ss += __shfl_xor(ss, off);
  float rn = sqrtf(1e-6f + ss);
  float ri = 1.f / rn;
  if (lane < 32) {
    ushort4 pk;
    pk.x = f2bf(v0 * ri); pk.y = f2bf(v1 * ri); pk.z = f2bf(v2 * ri); pk.w = f2bf(v3 * ri);
    *(ushort4*)(vbf + (size_t)n * 128 + dofs) = pk;
  }
  if (lane == 0) rnrm[n] = rn;
}

// ---------------- aggregation H=1 (layer 2): padded chunks of 16 ----------------
__global__ __launch_bounds__(256) void aggregate1(const unsigned short* __restrict__ featbf,
                                                  const float* __restrict__ ex1,
                                                  const int* __restrict__ csr_src,
                                                  const int* __restrict__ rsp,
                                                  const int* __restrict__ counts,
                                                  const float* __restrict__ res2,
                                                  float* __restrict__ out2, int Nn) {
  int n = (int)((blockIdx.x * blockDim.x + threadIdx.x) >> 6);
  if (n >= Nn) return;
  int lane = threadIdx.x & 63;
  int deg = counts[n], start = rsp[n];
  int chunks = (deg + 15) >> 4;
  int l16 = lane & 15;
  const float* exb = ex1 + start + l16;
  float dsum = 0.f;
  {
    float cur = exb[0];
    for (int c = 1; c < chunks; c++) {
      float nxt = exb[(size_t)c * 16];
      dsum += cur;
      cur = nxt;
    }
    if (chunks > 0) dsum += cur;
  }
#pragma unroll
  for (int off = 1; off < 16; off <<= 1) dsum += __shfl_xor(dsum, off);
  float inv = dsum > 0.f ? 1.f / dsum : 0.f;
  int g = lane >> 3, dofs = (lane & 7) << 2;
  const int* cs = csr_src + start + l16;
  int sv = cs[0];
  float av = exb[0];
  float a0 = 0.f, a1 = 0.f, a2 = 0.f, a3 = 0.f;
  for (int c = 0; c < chunks; c++) {
    int nsv = cs[(size_t)(c + 1) * 16];
    float nav = exb[(size_t)(c + 1) * 16];
    float aw_all = av * inv;
#pragma unroll
    for (int t = 0; t < 2; t++) {
      int j = (t << 3) + g;
      int sj = __shfl(sv, j);
      float aw = __shfl(aw_all, j);
      sj = sj > 0 ? sj : 0;
      uint2 u = *(const uint2*)(featbf + ((size_t)sj << 5) + dofs);
      a0 += aw * __uint_as_float(u.x << 16);
      a1 += aw * __uint_as_float(u.x & 0xffff0000u);
      a2 += aw * __uint_as_float(u.y << 16);
      a3 += aw * __uint_as_float(u.y & 0xffff0000u);
    }
    sv = nsv;
    av = nav;
  }
#pragma unroll
  for (int off = 8; off < 64; off <<= 1) {
    a0 += __shfl_xor(a0, off);
    a1 += __shfl_xor(a1, off);
    a2 += __shfl_xor(a2, off);
    a3 += __shfl_xor(a3, off);
  }
  if (lane < 8) {
    float4 rr = *(const float4*)(res2 + (size_t)n * 32 + dofs);
    float4 o;
    o.x = a0 + rr.x; o.y = a1 + rr.y; o.z = a2 + rr.z; o.w = a3 + rr.w;
    *(float4*)(out2 + (size_t)n * 32 + dofs) = o;
  }
}

// ---------------- PairNorm finish ----------------
__global__ __launch_bounds__(256) void colsum_k(const unsigned short* __restrict__ vbf,
                                                const float* __restrict__ rnrm,
                                                float* __restrict__ colsum, int Nn) {
  __shared__ float ls[256];
  int tid = threadIdx.x;
  int c = tid & 127, rsub = tid >> 7;
  float cs = 0.f;
  for (int r = blockIdx.x * 2 + rsub; r < Nn; r += gridDim.x * 2)
    cs += bf2f(vbf[(size_t)r * 128 + c]) * rnrm[r];
  ls[tid] = cs;
  __syncthreads();
  if (tid < 128) atomicAdd(&colsum[tid], ls[tid] + ls[tid + 128]);
}

__global__ __launch_bounds__(256) void sub_k(const unsigned short* __restrict__ vbf,
                                             const float* __restrict__ colsum,
                                             unsigned short* __restrict__ hbf, int Nn, float invN) {
  int t = blockIdx.x * 256 + threadIdx.x;   // one uint2 (4 cols) per thread
  if (t >= Nn * 32) return;
  int c4 = (t & 31) << 2;
  float4 m = *(const float4*)(colsum + c4);
  uint2 u = ((const uint2*)vbf)[t];
  unsigned int r0 = f2bf(__uint_as_float(u.x << 16) - m.x * invN);
  unsigned int r1 = f2bf(__uint_as_float(u.x & 0xffff0000u) - m.y * invN);
  unsigned int r2 = f2bf(__uint_as_float(u.y << 16) - m.z * invN);
  unsigned int r3 = f2bf(__uint_as_float(u.y & 0xffff0000u) - m.w * invN);
  uint2 o;
  o.x = r0 | (r1 << 16);
  o.y = r2 | (r3 << 16);
  ((uint2*)hbf)[t] = o;
}

// ---------------- final: mean over nodes of out2 ----------------
__global__ __launch_bounds__(256) void final_reduce(const float* __restrict__ out2,
                                                    float* __restrict__ outsum, int Nn) {
  __shared__ float ls[32];
  if (threadIdx.x < 32) ls[threadIdx.x] = 0.f;
  __syncthreads();
  int d = threadIdx.x & 31, rl = threadIdx.x >> 5;
  float acc = 0.f;
  for (int n = blockIdx.x * 8 + rl; n < Nn; n += gridDim.x * 8)
    acc += out2[(size_t)n * 32 + d];
  atomicAdd(&ls[d], acc);
  __syncthreads();
  if (threadIdx.x < 32) atomicAdd(&outsum[threadIdx.x], ls[threadIdx.x]);
}

__global__ void finalize_k(const float* __restrict__ outsum, float* __restrict__ out, float invN) {
  int t = threadIdx.x;
  if (t < 32) out[t] = outsum[t] * invN;
}

// ---------------- launcher ----------------
extern "C" void kernel_launch(void* const* d_in, const int* in_sizes, int n_in,
                              void* d_out, int out_size, void* d_ws, size_t ws_size,
                              hipStream_t stream) {
  const float* x     = (const float*)d_in[0];
  const int*   src   = (const int*)d_in[1];
  const int*   dst   = (const int*)d_in[2];
  const float* W0    = (const float*)d_in[3];
  const float* al0   = (const float*)d_in[4];
  const float* ar0   = (const float*)d_in[5];
  const float* W1    = (const float*)d_in[6];
  const float* al1   = (const float*)d_in[7];
  const float* ar1   = (const float*)d_in[8];
  const float* resW1 = (const float*)d_in[9];
  const float* W2    = (const float*)d_in[10];
  const float* al2   = (const float*)d_in[11];
  const float* ar2   = (const float*)d_in[12];
  const float* resW2 = (const float*)d_in[13];
  const int N = in_sizes[0] / 64;   // 100000
  const int E = in_sizes[1];        // 1600000
  const float invN = 1.f / (float)N;
  const int Emax = E + 15 * N + 1024;   // hard upper bound on padded slot count + margin
  int shift = 0;
  while (((unsigned)(N - 1) >> shift) > 7u) shift++;   // 8 dst-range buckets

  char* p = (char*)d_ws;
  auto alloc = [&](size_t bytes) { char* r = p; p += (bytes + 255) & ~(size_t)255; return r; };

  // zero-initialized region
  char* zbase = p;
  int*   counts  = (int*)alloc((size_t)4 * N);
  float* colsumA = (float*)alloc(512);
  float* colsumB = (float*)alloc(512);
  float* outsum  = (float*)alloc(128);
  size_t zbytes = (size_t)(p - zbase);

  int* rsp    = (int*)alloc((size_t)4 * N);     // padded row starts
  int* cursor = (int*)alloc((size_t)4 * N);
  int* bsum   = (int*)alloc(512);
  int* csr_src = (int*)alloc((size_t)4 * Emax);     // memset 0xFF: pads -1
  float* ex4  = (float*)alloc((size_t)16 * Emax);   // also ex1; hbf aliases its head
  unsigned short* hbf = (unsigned short*)ex4;       // safe: gemm_k reads hbf before alpha_k writes ex4
  unsigned short* featbf = (unsigned short*)alloc((size_t)2 * N * 128);
  unsigned short* vbf    = (unsigned short*)alloc((size_t)2 * N * 128);
  unsigned short* w0t = (unsigned short*)alloc((size_t)2 * 2 * 144 * 64);
  unsigned short* w1t = (unsigned short*)alloc((size_t)2 * 2 * 272 * 128);
  unsigned short* w2t = (unsigned short*)alloc((size_t)2 * 2 * 80 * 128);
  float* el4  = (float*)alloc((size_t)16 * N);
  float* er4  = (float*)alloc((size_t)16 * N);
  float* res  = (float*)alloc((size_t)4 * N * 128);  // layer-1 residual [N][128]
  float* rnrm = (float*)alloc((size_t)4 * N);
  float* res2 = res;                                 // layer-2 residual [N][32]
  float* out2 = res + (size_t)N * 32;                // layer-2 output   [N][32]

  hipMemsetAsync(zbase, 0, zbytes, stream);
  hipMemsetAsync(csr_src, 0xFF, (size_t)4 * Emax, stream);

  // CSR build (padded)
  int eb = (E + 255) / 256;
  int nb1024 = (N + 1023) / 1024;
  hist_k<<<eb, 256, 0, stream>>>(dst, counts, E);
  scan1<<<nb1024, 256, 0, stream>>>(counts, rsp, bsum, N);
  scan2<<<1, 128, 0, stream>>>(bsum, nb1024);
  scan3<<<(N + 255) / 256, 256, 0, stream>>>(rsp, bsum, cursor, N);
  pscatter_k<<<1024, 256, 0, stream>>>(src, dst, cursor, csr_src, E, shift);

  // weights: [W | W@al | W@ar | pad | resW] transposed, bf16 hi+lo; input cast
  fill_pack<<<(144 * 64 + 255) / 256, 256, 0, stream>>>(W0, al0, ar0, nullptr, w0t, 64, 144, 128, 4, 144);
  fill_pack<<<(272 * 128 + 255) / 256, 256, 0, stream>>>(W1, al1, ar1, resW1, w1t, 128, 272, 128, 4, 144);
  fill_pack<<<(80 * 128 + 255) / 256, 256, 0, stream>>>(W2, al2, ar2, resW2, w2t, 128, 80, 32, 1, 48);
  cast_f2bf_k<<<(N * 64 + 255) / 256, 256, 0, stream>>>(x, hbf, N * 64);

  const int rowTiles = N / 16;                  // 6250, divisible by R=5
  const int gblocks = (rowTiles / 5 + 3) / 4;   // 1250 waves, 4/block
  const int aggblocks = (N + 3) / 4;            // wave per node

  // Layer 0
  gemm_bf16<64, 144, 5, 128, 4, 144><<<gblocks, 256, 0, stream>>>(hbf, w0t, featbf, el4, er4, nullptr, rowTiles);
  alpha4_k<<<aggblocks, 256, 0, stream>>>(csr_src, el4, er4, ex4, rsp, counts, N);
  aggregate4<0><<<aggblocks, 256, 0, stream>>>(featbf, ex4, csr_src, rsp, counts, nullptr, vbf, rnrm, N);
  colsum_k<<<512, 256, 0, stream>>>(vbf, rnrm, colsumA, N);
  sub_k<<<(N * 32 + 255) / 256, 256, 0, stream>>>(vbf, colsumA, hbf, N, invN);

  // Layer 1
  gemm_bf16<128, 272, 5, 128, 4, 144><<<gblocks, 256, 0, stream>>>(hbf, w1t, featbf, el4, er4, res, rowTiles);
  alpha4_k<<<aggblocks, 256, 0, stream>>>(csr_src, el4, er4, ex4, rsp, counts, N);
  aggregate4<1><<<aggblocks, 256, 0, stream>>>(featbf, ex4, csr_src, rsp, counts, res, vbf, rnrm, N);
  colsum_k<<<512, 256, 0, stream>>>(vbf, rnrm, colsumB, N);
  sub_k<<<(N * 32 + 255) / 256, 256, 0, stream>>>(vbf, colsumB, hbf, N, invN);

  // Layer 2
  gemm_bf16<128, 80, 5, 32, 1, 48><<<gblocks, 256, 0, stream>>>(hbf, w2t, featbf, el4, er4, res2, rowTiles);
  alpha1_k<<<aggblocks, 256, 0, stream>>>(csr_src, el4, er4, ex4, rsp, counts, N);
  aggregate1<<<aggblocks, 256, 0, stream>>>(featbf, ex4, csr_src, rsp, counts, res2, out2, N);
  final_reduce<<<512, 256, 0, stream>>>(out2, outsum, N);
  finalize_k<<<1, 64, 0, stream>>>(outsum, (float*)d_out, invN);
}

// Round 6
// 658.346 us; speedup vs baseline: 1.8551x; 1.1396x over previous
//
#include <hip/hip_runtime.h>

// GAT 3-layer forward on MI355X — round 6.
// vs round 5: (1) XCD-affine scatter (bucket = blockIdx&7 so each csr line is owned by
// one XCD L2 -> full-line evictions; R5 showed 88MB writes for 13MB array because all
// 8 non-coherent L2s held partial copies). (2) single-pass fused aggregation: alpha
// (exp) computed in-loop, denominator and unnormalized accumulation in the same chunk
// sweep, normalize at the end -> alpha kernels and the 50MB ex array are gone; phase B
// is one-edge-per-wave so csr reads become batched scalar loads.

typedef __attribute__((ext_vector_type(8))) short s8v;
typedef __attribute__((ext_vector_type(4))) float f4v;

__device__ __forceinline__ unsigned short f2bf(float f) {
  unsigned int x = __float_as_uint(f);
  x += 0x7fffu + ((x >> 16) & 1u);          // RTNE
  return (unsigned short)(x >> 16);
}
__device__ __forceinline__ float bf2f(unsigned short u) {
  return __uint_as_float(((unsigned int)u) << 16);
}
__device__ __forceinline__ float lrelu(float x) { return x > 0.f ? x : 0.2f * x; }
__device__ __forceinline__ float elu1(float x) { return x > 0.f ? x : expm1f(x); }

// ---------------- CSR build (padded to multiples of 16 per node) ----------------
__global__ __launch_bounds__(256) void hist_k(const int* __restrict__ dst, int* __restrict__ counts, int E) {
  int t = blockIdx.x * 256 + threadIdx.x;
  if (t < E) atomicAdd(&counts[dst[t]], 1);
}

__global__ __launch_bounds__(256) void scan1(const int* __restrict__ counts, int* __restrict__ rsp,
                                             int* __restrict__ bsum, int Nn) {
  __shared__ int s[256];
  int t = threadIdx.x;
  int base = blockIdx.x * 1024 + t * 4;
  int v0 = (base + 0 < Nn) ? ((counts[base + 0] + 15) & ~15) : 0;
  int v1 = (base + 1 < Nn) ? ((counts[base + 1] + 15) & ~15) : 0;
  int v2 = (base + 2 < Nn) ? ((counts[base + 2] + 15) & ~15) : 0;
  int v3 = (base + 3 < Nn) ? ((counts[base + 3] + 15) & ~15) : 0;
  s[t] = v0 + v1 + v2 + v3;
  __syncthreads();
  for (int off = 1; off < 256; off <<= 1) {
    int xv = (t >= off) ? s[t - off] : 0;
    __syncthreads();
    s[t] += xv;
    __syncthreads();
  }
  int excl = t ? s[t - 1] : 0;
  if (t == 255) bsum[blockIdx.x] = s[255];
  if (base + 0 < Nn) { rsp[base + 0] = excl; excl += v0; }
  if (base + 1 < Nn) { rsp[base + 1] = excl; excl += v1; }
  if (base + 2 < Nn) { rsp[base + 2] = excl; excl += v2; }
  if (base + 3 < Nn) { rsp[base + 3] = excl; }
}

__global__ __launch_bounds__(128) void scan2(int* __restrict__ bsum, int nb) {
  __shared__ int s[128];
  int t = threadIdx.x;
  s[t] = (t < nb) ? bsum[t] : 0;
  __syncthreads();
  for (int off = 1; off < 128; off <<= 1) {
    int xv = (t >= off) ? s[t - off] : 0;
    __syncthreads();
    s[t] += xv;
    __syncthreads();
  }
  if (t < nb) bsum[t] = t ? s[t - 1] : 0;
}

__global__ __launch_bounds__(256) void scan3(int* __restrict__ rsp, const int* __restrict__ bsum,
                                             int* __restrict__ cursor, int Nn) {
  int t = blockIdx.x * 256 + threadIdx.x;
  if (t < Nn) {
    int v = rsp[t] + bsum[t >> 10];
    rsp[t] = v;
    cursor[t] = v;
  }
}

// XCD-affine scatter: bucket p = blockIdx&7; consecutive blocks round-robin XCDs, so
// bucket p's csr region lives in exactly one XCD's L2 -> lines evict once, full.
__global__ __launch_bounds__(256) void pscatter_k(const int* __restrict__ src, const int* __restrict__ dst,
                                                  int* __restrict__ cursor, int* __restrict__ csr_src,
                                                  int E, int shift) {
  int p = blockIdx.x & 7;
  int pb = blockIdx.x >> 3;
  int stride = (gridDim.x >> 3) * 256;
  for (int e = pb * 256 + threadIdx.x; e < E; e += stride) {
    int d = dst[e];
    if ((d >> shift) == p) {
      int pos = atomicAdd(&cursor[d], 1);
      csr_src[pos] = src[e];
    }
  }
}

// ---------------- fused weight pack: [W | W@al | W@ar | pad | resW], bf16 hi+lo ----------------
__global__ __launch_bounds__(256) void fill_pack(const float* __restrict__ W, const float* __restrict__ al,
                                                 const float* __restrict__ ar, const float* __restrict__ resW,
                                                 unsigned short* __restrict__ out,
                                                 int K, int M, int BF, int H, int RES0) {
  int t = blockIdx.x * 256 + threadIdx.x;
  if (t >= K * M) return;
  int c = t / K, k = t - c * K;
  float v = 0.f;
  if (c < BF) {
    v = W[k * BF + c];
  } else if (c < BF + H) {
    int h = c - BF;
    float s = 0.f;
    for (int d = 0; d < 32; d++) s += W[k * BF + h * 32 + d] * al[h * 32 + d];
    v = s;
  } else if (c < BF + 2 * H) {
    int h = c - BF - H;
    float s = 0.f;
    for (int d = 0; d < 32; d++) s += W[k * BF + h * 32 + d] * ar[h * 32 + d];
    v = s;
  } else if (c >= RES0) {
    v = resW[k * (M - RES0) + (c - RES0)];
  }
  unsigned short hi = f2bf(v);
  out[c * K + k] = hi;
  out[M * K + c * K + k] = f2bf(v - bf2f(hi));
}

__global__ __launch_bounds__(256) void cast_f2bf_k(const float* __restrict__ x, unsigned short* __restrict__ y, int n) {
  int t = blockIdx.x * 256 + threadIdx.x;
  if (t < n) y[t] = f2bf(x[t]);
}

// ---------------- GEMM: A[N,K](bf16) @ Bt[M,K](bf16 hi+lo) ----------------
template <int K, int M, int R, int BF, int H, int RES0>
__global__ __launch_bounds__(256) void gemm_bf16(const unsigned short* __restrict__ A,
                                                 const unsigned short* __restrict__ Bt,
                                                 unsigned short* __restrict__ featbf,
                                                 float* __restrict__ el, float* __restrict__ er,
                                                 float* __restrict__ res, int nRowTiles) {
  int wv = (int)((blockIdx.x * blockDim.x + threadIdx.x) >> 6);
  int tile0 = wv * R;
  if (tile0 >= nRowTiles) return;
  int lane = threadIdx.x & 63;
  int r = lane & 15, q = lane >> 4;
  s8v afrag[R][K / 32];
#pragma unroll
  for (int rr = 0; rr < R; rr++) {
    const unsigned short* arow = A + (size_t)((tile0 + rr) * 16 + r) * K + q * 8;
#pragma unroll
    for (int kk = 0; kk < K / 32; kk++) afrag[rr][kk] = *(const s8v*)(arow + kk * 32);
  }
#pragma unroll
  for (int ct = 0; ct < M / 16; ct++) {
    const unsigned short* brow = Bt + (size_t)(ct * 16 + r) * K + q * 8;
    s8v bhi[K / 32], blo[K / 32];
#pragma unroll
    for (int kk = 0; kk < K / 32; kk++) {
      bhi[kk] = *(const s8v*)(brow + kk * 32);
      blo[kk] = *(const s8v*)(brow + (size_t)M * K + kk * 32);
    }
    int col = ct * 16 + r;
#pragma unroll
    for (int rr = 0; rr < R; rr++) {
      f4v acc = {0.f, 0.f, 0.f, 0.f};
#pragma unroll
      for (int kk = 0; kk < K / 32; kk++) {
        acc = __builtin_amdgcn_mfma_f32_16x16x32_bf16(afrag[rr][kk], bhi[kk], acc, 0, 0, 0);
        acc = __builtin_amdgcn_mfma_f32_16x16x32_bf16(afrag[rr][kk], blo[kk], acc, 0, 0, 0);
      }
      int row0 = (tile0 + rr) * 16 + q * 4;
#pragma unroll
      for (int i = 0; i < 4; i++) {
        float v = acc[i];
        size_t row = (size_t)(row0 + i);
        if (col < BF) {
          featbf[row * BF + col] = f2bf(v);
        } else if (col < BF + H) {
          el[row * H + (col - BF)] = v;
        } else if (col < BF + 2 * H) {
          er[row * H + (col - BF - H)] = v;
        } else if (RES0 < M && col >= RES0) {
          res[row * (M - RES0) + (col - RES0)] = v;
        }
      }
    }
  }
}

// ---------------- fused single-pass aggregation H=4 ----------------
// Per chunk of 16 edges: phase A (slot x head layout) computes ex = exp(lrelu(el+er))
// in registers and accumulates the denominator; phase B (one edge per wave, lane owns
// dims {2l,2l+1}) accumulates UNNORMALIZED ex*feat with sj from batched scalar loads.
// Normalize by 1/denom at the end, then residual+ELU+rownorm epilogue, bf16 write.
template <int MODE>
__global__ __launch_bounds__(256) void aggregate4(const unsigned short* __restrict__ featbf,
                                                  const float* __restrict__ el4,
                                                  const float* __restrict__ er4,
                                                  const int* __restrict__ csr_src,
                                                  const int* __restrict__ rsp,
                                                  const int* __restrict__ counts,
                                                  const float* __restrict__ res,
                                                  unsigned short* __restrict__ vbf,
                                                  float* __restrict__ rnrm, int Nn) {
  int n = (int)((blockIdx.x * blockDim.x + threadIdx.x) >> 6);
  if (n >= Nn) return;
  int lane = threadIdx.x & 63;
  int start = __builtin_amdgcn_readfirstlane(rsp[n]);
  int chunks = __builtin_amdgcn_readfirstlane((counts[n] + 15) >> 4);
  int slot = lane >> 2, h = lane & 3;
  float ern = er4[(size_t)n * 4 + h];
  int hl = lane >> 4;                       // head owned in dim layout (lane's dims 2l,2l+1)
  int dby = lane << 2;                      // byte offset into 256B feat row
  float a0 = 0.f, a1 = 0.f, dsum = 0.f;
  for (int c = 0; c < chunks; c++) {
    int cbase = start + c * 16;
    // phase A: one (edge,head) per lane
    int sA = csr_src[cbase + slot];
    float exv = 0.f;
    if (sA >= 0) {
      float e = el4[(size_t)sA * 4 + h] + ern;
      exv = __expf(e > 0.f ? e : 0.2f * e);
    }
    dsum += exv;
    // phase B: 16 edges, whole wave per edge; sj wave-uniform -> scalar loads
    const int* csp = csr_src + cbase;
    int sj[16];
#pragma unroll
    for (int j = 0; j < 16; j++) sj[j] = csp[j];
#pragma unroll
    for (int j = 0; j < 16; j++) {
      float aw = __shfl(exv, (j << 2) | hl);
      int sjc = sj[j] > 0 ? sj[j] : 0;      // pad src=-1 -> 0 (aw=0 there)
      unsigned int u = *(const unsigned int*)((const char*)featbf + ((size_t)sjc << 8) + dby);
      a0 += aw * __uint_as_float(u << 16);
      a1 += aw * __uint_as_float(u & 0xffff0000u);
    }
  }
#pragma unroll
  for (int off = 4; off < 64; off <<= 1) dsum += __shfl_xor(dsum, off);  // per-head totals
  float inv = dsum > 0.f ? 1.f / dsum : 0.f;                             // lane l: head l&3
  float invh = __shfl(inv, hl);
  a0 *= invh;
  a1 *= invh;
  float v0, v1;
  if (MODE == 1) {
    float2 rr = *(const float2*)((const char*)res + ((size_t)n << 9) + (lane << 3));
    v0 = elu1(elu1(a0 + rr.x));
    v1 = elu1(elu1(a1 + rr.y));
  } else {
    v0 = elu1(a0);
    v1 = elu1(a1);
  }
  float ss = v0 * v0 + v1 * v1;
#pragma unroll
  for (int off = 1; off < 64; off <<= 1) ss += __shfl_xor(ss, off);
  float rn = sqrtf(1e-6f + ss);
  float ri = 1.f / rn;
  unsigned int pk = (unsigned int)f2bf(v0 * ri) | ((unsigned int)f2bf(v1 * ri) << 16);
  *(unsigned int*)((char*)vbf + ((size_t)n << 8) + (lane << 2)) = pk;
  if (lane == 0) rnrm[n] = rn;
}

// ---------------- fused single-pass aggregation H=1 (layer 2) ----------------
__global__ __launch_bounds__(256) void aggregate1(const unsigned short* __restrict__ featbf,
                                                  const float* __restrict__ el1,
                                                  const float* __restrict__ er1,
                                                  const int* __restrict__ csr_src,
                                                  const int* __restrict__ rsp,
                                                  const int* __restrict__ counts,
                                                  const float* __restrict__ res2,
                                                  float* __restrict__ out2, int Nn) {
  int n = (int)((blockIdx.x * blockDim.x + threadIdx.x) >> 6);
  if (n >= Nn) return;
  int lane = threadIdx.x & 63;
  int start = __builtin_amdgcn_readfirstlane(rsp[n]);
  int chunks = __builtin_amdgcn_readfirstlane((counts[n] + 15) >> 4);
  int l16 = lane & 15;
  float ern = er1[n];
  int g = lane >> 3, dofs = (lane & 7) << 2;
  float a0 = 0.f, a1 = 0.f, a2 = 0.f, a3 = 0.f, dsum = 0.f;
  for (int c = 0; c < chunks; c++) {
    int cbase = start + c * 16;
    int sA = csr_src[cbase + l16];
    float exv = 0.f;
    if (sA >= 0) exv = __expf(lrelu(el1[sA] + ern));
    dsum += exv;
#pragma unroll
    for (int t = 0; t < 2; t++) {
      int j = (t << 3) + g;
      int sj = __shfl(sA, j);
      float aw = __shfl(exv, j);
      sj = sj > 0 ? sj : 0;
      uint2 u = *(const uint2*)(featbf + ((size_t)sj << 5) + dofs);
      a0 += aw * __uint_as_float(u.x << 16);
      a1 += aw * __uint_as_float(u.x & 0xffff0000u);
      a2 += aw * __uint_as_float(u.y << 16);
      a3 += aw * __uint_as_float(u.y & 0xffff0000u);
    }
  }
#pragma unroll
  for (int off = 1; off < 16; off <<= 1) dsum += __shfl_xor(dsum, off);
  float inv = dsum > 0.f ? 1.f / dsum : 0.f;
#pragma unroll
  for (int off = 8; off < 64; off <<= 1) {
    a0 += __shfl_xor(a0, off);
    a1 += __shfl_xor(a1, off);
    a2 += __shfl_xor(a2, off);
    a3 += __shfl_xor(a3, off);
  }
  if (lane < 8) {
    float4 rr = *(const float4*)(res2 + (size_t)n * 32 + dofs);
    float4 o;
    o.x = a0 * inv + rr.x;
    o.y = a1 * inv + rr.y;
    o.z = a2 * inv + rr.z;
    o.w = a3 * inv + rr.w;
    *(float4*)(out2 + (size_t)n * 32 + dofs) = o;
  }
}

// ---------------- PairNorm finish ----------------
__global__ __launch_bounds__(256) void colsum_k(const unsigned short* __restrict__ vbf,
                                                const float* __restrict__ rnrm,
                                                float* __restrict__ colsum, int Nn) {
  __shared__ float ls[256];
  int tid = threadIdx.x;
  int c = tid & 127, rsub = tid >> 7;
  float cs = 0.f;
  for (int r = blockIdx.x * 2 + rsub; r < Nn; r += gridDim.x * 2)
    cs += bf2f(vbf[(size_t)r * 128 + c]) * rnrm[r];
  ls[tid] = cs;
  __syncthreads();
  if (tid < 128) atomicAdd(&colsum[tid], ls[tid] + ls[tid + 128]);
}

__global__ __launch_bounds__(256) void sub_k(const unsigned short* __restrict__ vbf,
                                             const float* __restrict__ colsum,
                                             unsigned short* __restrict__ hbf, int Nn, float invN) {
  int t = blockIdx.x * 256 + threadIdx.x;   // one uint2 (4 cols) per thread
  if (t >= Nn * 32) return;
  int c4 = (t & 31) << 2;
  float4 m = *(const float4*)(colsum + c4);
  uint2 u = ((const uint2*)vbf)[t];
  unsigned int r0 = f2bf(__uint_as_float(u.x << 16) - m.x * invN);
  unsigned int r1 = f2bf(__uint_as_float(u.x & 0xffff0000u) - m.y * invN);
  unsigned int r2 = f2bf(__uint_as_float(u.y << 16) - m.z * invN);
  unsigned int r3 = f2bf(__uint_as_float(u.y & 0xffff0000u) - m.w * invN);
  uint2 o;
  o.x = r0 | (r1 << 16);
  o.y = r2 | (r3 << 16);
  ((uint2*)hbf)[t] = o;
}

// ---------------- final: mean over nodes of out2 ----------------
__global__ __launch_bounds__(256) void final_reduce(const float* __restrict__ out2,
                                                    float* __restrict__ outsum, int Nn) {
  __shared__ float ls[32];
  if (threadIdx.x < 32) ls[threadIdx.x] = 0.f;
  __syncthreads();
  int d = threadIdx.x & 31, rl = threadIdx.x >> 5;
  float acc = 0.f;
  for (int n = blockIdx.x * 8 + rl; n < Nn; n += gridDim.x * 8)
    acc += out2[(size_t)n * 32 + d];
  atomicAdd(&ls[d], acc);
  __syncthreads();
  if (threadIdx.x < 32) atomicAdd(&outsum[threadIdx.x], ls[threadIdx.x]);
}

__global__ void finalize_k(const float* __restrict__ outsum, float* __restrict__ out, float invN) {
  int t = threadIdx.x;
  if (t < 32) out[t] = outsum[t] * invN;
}

// ---------------- launcher ----------------
extern "C" void kernel_launch(void* const* d_in, const int* in_sizes, int n_in,
                              void* d_out, int out_size, void* d_ws, size_t ws_size,
                              hipStream_t stream) {
  const float* x     = (const float*)d_in[0];
  const int*   src   = (const int*)d_in[1];
  const int*   dst   = (const int*)d_in[2];
  const float* W0    = (const float*)d_in[3];
  const float* al0   = (const float*)d_in[4];
  const float* ar0   = (const float*)d_in[5];
  const float* W1    = (const float*)d_in[6];
  const float* al1   = (const float*)d_in[7];
  const float* ar1   = (const float*)d_in[8];
  const float* resW1 = (const float*)d_in[9];
  const float* W2    = (const float*)d_in[10];
  const float* al2   = (const float*)d_in[11];
  const float* ar2   = (const float*)d_in[12];
  const float* resW2 = (const float*)d_in[13];
  const int N = in_sizes[0] / 64;   // 100000
  const int E = in_sizes[1];        // 1600000
  const float invN = 1.f / (float)N;
  const int Emax = E + 15 * N + 1024;   // upper bound on padded slot count + margin
  int shift = 0;
  while (((unsigned)(N - 1) >> shift) > 7u) shift++;   // 8 dst-range buckets

  char* p = (char*)d_ws;
  auto alloc = [&](size_t bytes) { char* r = p; p += (bytes + 255) & ~(size_t)255; return r; };

  // zero-initialized region
  char* zbase = p;
  int*   counts  = (int*)alloc((size_t)4 * N);
  float* colsumA = (float*)alloc(512);
  float* colsumB = (float*)alloc(512);
  float* outsum  = (float*)alloc(128);
  size_t zbytes = (size_t)(p - zbase);

  int* rsp    = (int*)alloc((size_t)4 * N);     // padded row starts
  int* cursor = (int*)alloc((size_t)4 * N);
  int* bsum   = (int*)alloc(512);
  int* csr_src = (int*)alloc((size_t)4 * Emax);     // memset 0xFF: pads -1
  unsigned short* hbf    = (unsigned short*)alloc((size_t)2 * N * 128);
  unsigned short* featbf = (unsigned short*)alloc((size_t)2 * N * 128);
  unsigned short* vbf    = (unsigned short*)alloc((size_t)2 * N * 128);
  unsigned short* w0t = (unsigned short*)alloc((size_t)2 * 2 * 144 * 64);
  unsigned short* w1t = (unsigned short*)alloc((size_t)2 * 2 * 272 * 128);
  unsigned short* w2t = (unsigned short*)alloc((size_t)2 * 2 * 80 * 128);
  float* el4  = (float*)alloc((size_t)16 * N);
  float* er4  = (float*)alloc((size_t)16 * N);
  float* res  = (float*)alloc((size_t)4 * N * 128);  // layer-1 residual [N][128]
  float* rnrm = (float*)alloc((size_t)4 * N);
  float* res2 = res;                                 // layer-2 residual [N][32]
  float* out2 = res + (size_t)N * 32;                // layer-2 output   [N][32]

  hipMemsetAsync(zbase, 0, zbytes, stream);
  hipMemsetAsync(csr_src, 0xFF, (size_t)4 * Emax, stream);

  // CSR build (padded)
  int eb = (E + 255) / 256;
  int nb1024 = (N + 1023) / 1024;
  hist_k<<<eb, 256, 0, stream>>>(dst, counts, E);
  scan1<<<nb1024, 256, 0, stream>>>(counts, rsp, bsum, N);
  scan2<<<1, 128, 0, stream>>>(bsum, nb1024);
  scan3<<<(N + 255) / 256, 256, 0, stream>>>(rsp, bsum, cursor, N);
  pscatter_k<<<1024, 256, 0, stream>>>(src, dst, cursor, csr_src, E, shift);

  // weights: [W | W@al | W@ar | pad | resW] transposed, bf16 hi+lo; input cast
  fill_pack<<<(144 * 64 + 255) / 256, 256, 0, stream>>>(W0, al0, ar0, nullptr, w0t, 64, 144, 128, 4, 144);
  fill_pack<<<(272 * 128 + 255) / 256, 256, 0, stream>>>(W1, al1, ar1, resW1, w1t, 128, 272, 128, 4, 144);
  fill_pack<<<(80 * 128 + 255) / 256, 256, 0, stream>>>(W2, al2, ar2, resW2, w2t, 128, 80, 32, 1, 48);
  cast_f2bf_k<<<(N * 64 + 255) / 256, 256, 0, stream>>>(x, hbf, N * 64);

  const int rowTiles = N / 16;                  // 6250, divisible by R=5
  const int gblocks = (rowTiles / 5 + 3) / 4;   // 1250 waves, 4/block
  const int aggblocks = (N + 3) / 4;            // wave per node

  // Layer 0
  gemm_bf16<64, 144, 5, 128, 4, 144><<<gblocks, 256, 0, stream>>>(hbf, w0t, featbf, el4, er4, nullptr, rowTiles);
  aggregate4<0><<<aggblocks, 256, 0, stream>>>(featbf, el4, er4, csr_src, rsp, counts, nullptr, vbf, rnrm, N);
  colsum_k<<<512, 256, 0, stream>>>(vbf, rnrm, colsumA, N);
  sub_k<<<(N * 32 + 255) / 256, 256, 0, stream>>>(vbf, colsumA, hbf, N, invN);

  // Layer 1
  gemm_bf16<128, 272, 5, 128, 4, 144><<<gblocks, 256, 0, stream>>>(hbf, w1t, featbf, el4, er4, res, rowTiles);
  aggregate4<1><<<aggblocks, 256, 0, stream>>>(featbf, el4, er4, csr_src, rsp, counts, res, vbf, rnrm, N);
  colsum_k<<<512, 256, 0, stream>>>(vbf, rnrm, colsumB, N);
  sub_k<<<(N * 32 + 255) / 256, 256, 0, stream>>>(vbf, colsumB, hbf, N, invN);

  // Layer 2
  gemm_bf16<128, 80, 5, 32, 1, 48><<<gblocks, 256, 0, stream>>>(hbf, w2t, featbf, el4, er4, res2, rowTiles);
  aggregate1<<<aggblocks, 256, 0, stream>>>(featbf, el4, er4, csr_src, rsp, counts, res2, out2, N);
  final_reduce<<<512, 256, 0, stream>>>(out2, outsum, N);
  finalize_k<<<1, 64, 0, stream>>>(outsum, (float*)d_out, invN);
}